// Round 1
// baseline (209.009 us; speedup 1.0000x reference)
//
#include <hip/hip_runtime.h>
#include <math.h>

// Problem constants
#define NROWS 8192
#define DIN   256
#define DP    64
#define NH    8
#define NC    128
#define DOUT  256

// ---------------------------------------------------------------------------
// Prep: WvSum (reduce Wv over g) + Ov packed into W2[h][c][128], ctr bias.
// grid = NH*NC blocks (1024), 64 threads (=p)
// ---------------------------------------------------------------------------
__global__ __launch_bounds__(64) void prep_kernel(
    const float* __restrict__ ctrs,
    const float* __restrict__ Wv,
    const float* __restrict__ Ov,
    float* __restrict__ W2,
    float* __restrict__ cbias) {
  int b = blockIdx.x;        // h*NC + c
  int t = threadIdx.x;       // p
  // centroid bias = -||ctr||^2
  float v = ctrs[(size_t)b * 64 + t];
  float sq = v * v;
  #pragma unroll
  for (int off = 32; off >= 1; off >>= 1) sq += __shfl_xor(sq, off, 64);
  if (t == 0) cbias[b] = -sq;
  // WvSum over g
  const float* wv = Wv + (size_t)b * 64 * 64;
  float acc = 0.f;
  #pragma unroll 8
  for (int g = 0; g < 64; ++g) acc += wv[g * 64 + t];
  W2[(size_t)b * 128 + t]      = acc;
  W2[(size_t)b * 128 + 64 + t] = Ov[(size_t)b * 64 + t];
}

// ---------------------------------------------------------------------------
// Transpose Wq (DIN, DP, NH) -> Wqt[k][j], j = h*64+p. 131072 elems.
// ---------------------------------------------------------------------------
__global__ __launch_bounds__(256) void wqt_kernel(
    const float* __restrict__ Wq, float* __restrict__ Wqt) {
  int idx = blockIdx.x * 256 + threadIdx.x;   // < 131072
  int k = idx >> 9, j = idx & 511;
  Wqt[idx] = Wq[(k << 9) + ((j & 63) << 3) + (j >> 6)];
}

// ---------------------------------------------------------------------------
// f32 GEMM: C[M x N] = A[M x K] * B[K x N], all row-major.
// BM=128, BN=64, BK=16; 256 threads; thread tile 8x4.
// grid = dim3(N/64, M/128)
// ---------------------------------------------------------------------------
#define BM 128
#define BN 64
#define BK 16

__global__ __launch_bounds__(256) void gemm_kernel(
    const float* __restrict__ A, const float* __restrict__ B,
    float* __restrict__ C, int K, int lda, int ldb, int ldc) {
  __shared__ float sA[BK][BM + 4];
  __shared__ float sB[BK][BN + 4];
  const int t = threadIdx.x;
  const int m0 = blockIdx.y * BM;
  const int n0 = blockIdx.x * BN;
  const int ty = t >> 4;   // 0..15 -> rows ty*8..
  const int tx = t & 15;   // 0..15 -> cols tx*4..

  float acc[8][4];
  #pragma unroll
  for (int r = 0; r < 8; ++r)
    #pragma unroll
    for (int c = 0; c < 4; ++c) acc[r][c] = 0.f;

  for (int k0 = 0; k0 < K; k0 += BK) {
    // stage A tile 128x16 (512 float4, 2 per thread), transposed into sA[k][m]
    #pragma unroll
    for (int i = 0; i < 2; ++i) {
      int q = t + i * 256;
      int row = q >> 2, kf = (q & 3) << 2;
      float4 v = *(const float4*)(A + (size_t)(m0 + row) * lda + k0 + kf);
      sA[kf + 0][row] = v.x;
      sA[kf + 1][row] = v.y;
      sA[kf + 2][row] = v.z;
      sA[kf + 3][row] = v.w;
    }
    // stage B tile 16x64 (256 float4, 1 per thread)
    {
      int kk = t >> 4, jf = (t & 15) << 2;
      *(float4*)&sB[kk][jf] = *(const float4*)(B + (size_t)(k0 + kk) * ldb + n0 + jf);
    }
    __syncthreads();
    #pragma unroll
    for (int k = 0; k < BK; ++k) {
      float4 a0 = *(const float4*)&sA[k][ty * 8];
      float4 a1 = *(const float4*)&sA[k][ty * 8 + 4];
      float4 b4 = *(const float4*)&sB[k][tx * 4];
      float ar[8] = {a0.x, a0.y, a0.z, a0.w, a1.x, a1.y, a1.z, a1.w};
      float bc[4] = {b4.x, b4.y, b4.z, b4.w};
      #pragma unroll
      for (int r = 0; r < 8; ++r)
        #pragma unroll
        for (int c = 0; c < 4; ++c)
          acc[r][c] = fmaf(ar[r], bc[c], acc[r][c]);
    }
    __syncthreads();
  }
  #pragma unroll
  for (int r = 0; r < 8; ++r) {
    float4 v = make_float4(acc[r][0], acc[r][1], acc[r][2], acc[r][3]);
    *(float4*)(C + (size_t)(m0 + ty * 8 + r) * ldc + n0 + tx * 4) = v;
  }
}

// ---------------------------------------------------------------------------
// Fused: logits (2*x_in.ctr + bias) -> softmax over c -> [t1|t2] = a@W2 ->
//        ho[h][n][p] = x_in*t1 + t2
// grid = NH * (NROWS/32) = 2048 blocks, 256 threads, 32 rows per block.
// ---------------------------------------------------------------------------
__global__ __launch_bounds__(256) void fused_kernel(
    const float* __restrict__ xin,   // [N][512], col j=h*64+p
    const float* __restrict__ ctrs,  // [h][c][p]
    const float* __restrict__ cbias, // [h][c]
    const float* __restrict__ W2,    // [h][c][128]
    float* __restrict__ ho) {        // [h][n][p]
  const int b = blockIdx.x;
  const int h = b >> 8;
  const int n0 = (b & 255) * 32;
  const int t = threadIdx.x;

  __shared__ float s_xin[32][68];
  __shared__ float s_as[32][132];
  __shared__ float s_T[32][132];
  __shared__ float s_un[8704];   // union: ctr[128][68] (8704) / w[64][132] (8448)

  // stage x_in tile (32x64)
  #pragma unroll
  for (int i = 0; i < 2; ++i) {
    int f = i * 256 + t;
    int n = f >> 4, pf = (f & 15) << 2;
    *(float4*)&s_xin[n][pf] =
        *(const float4*)(xin + (size_t)(n0 + n) * 512 + h * 64 + pf);
  }
  // stage centroids (128x64)
  float* s_ctr = s_un;
  #pragma unroll
  for (int i = 0; i < 8; ++i) {
    int f = i * 256 + t;
    int c = f >> 4, pf = (f & 15) << 2;
    *(float4*)&s_ctr[c * 68 + pf] =
        *(const float4*)(ctrs + ((size_t)(h * NC + c)) * 64 + pf);
  }
  __syncthreads();

  const int ty = t >> 5;   // 0..7  -> rows ty*4..
  const int tx = t & 31;   // 0..31 -> cols tx*4..

  // ---- logits: 32x128, K=64 ----
  {
    float acc[4][4];
    #pragma unroll
    for (int r = 0; r < 4; ++r)
      #pragma unroll
      for (int c = 0; c < 4; ++c) acc[r][c] = 0.f;
    #pragma unroll
    for (int k4 = 0; k4 < 16; ++k4) {
      float4 av[4], cv[4];
      #pragma unroll
      for (int r = 0; r < 4; ++r)
        av[r] = *(const float4*)&s_xin[ty * 4 + r][k4 * 4];
      #pragma unroll
      for (int c = 0; c < 4; ++c)
        cv[c] = *(const float4*)&s_ctr[(tx * 4 + c) * 68 + k4 * 4];
      #pragma unroll
      for (int r = 0; r < 4; ++r) {
        #pragma unroll
        for (int c = 0; c < 4; ++c) {
          acc[r][c] += av[r].x * cv[c].x + av[r].y * cv[c].y +
                       av[r].z * cv[c].z + av[r].w * cv[c].w;
        }
      }
    }
    float b0 = cbias[h * NC + tx * 4 + 0];
    float b1 = cbias[h * NC + tx * 4 + 1];
    float b2 = cbias[h * NC + tx * 4 + 2];
    float b3 = cbias[h * NC + tx * 4 + 3];
    #pragma unroll
    for (int r = 0; r < 4; ++r) {
      float4 v = make_float4(2.f * acc[r][0] + b0, 2.f * acc[r][1] + b1,
                             2.f * acc[r][2] + b2, 2.f * acc[r][3] + b3);
      *(float4*)&s_as[ty * 4 + r][tx * 4] = v;
    }
  }
  __syncthreads();

  // ---- softmax over c per row: 8 lanes per row ----
  {
    int row = t >> 3, sub = t & 7;
    float vals[16];
    float m = -1e30f;
    #pragma unroll
    for (int i = 0; i < 16; ++i) {
      vals[i] = s_as[row][sub + i * 8];
      m = fmaxf(m, vals[i]);
    }
    #pragma unroll
    for (int off = 1; off < 8; off <<= 1) m = fmaxf(m, __shfl_xor(m, off, 64));
    float s = 0.f;
    #pragma unroll
    for (int i = 0; i < 16; ++i) {
      vals[i] = __expf(vals[i] - m);
      s += vals[i];
    }
    #pragma unroll
    for (int off = 1; off < 8; off <<= 1) s += __shfl_xor(s, off, 64);
    float inv = 1.f / s;
    #pragma unroll
    for (int i = 0; i < 16; ++i) s_as[row][sub + i * 8] = vals[i] * inv;
  }
  __syncthreads();

  // ---- T = a @ W2_h : 32x128, K=128 (two halves of 64 staged in LDS) ----
  float accT[4][4];
  #pragma unroll
  for (int r = 0; r < 4; ++r)
    #pragma unroll
    for (int c = 0; c < 4; ++c) accT[r][c] = 0.f;
  float* s_w = s_un;
  for (int half = 0; half < 2; ++half) {
    if (half) __syncthreads();
    #pragma unroll
    for (int i = 0; i < 8; ++i) {
      int f = i * 256 + t;
      int cc = f >> 5, qf = (f & 31) << 2;
      *(float4*)&s_w[cc * 132 + qf] =
          *(const float4*)(W2 + ((size_t)(h * NC + half * 64 + cc)) * 128 + qf);
    }
    __syncthreads();
    #pragma unroll
    for (int c4 = 0; c4 < 16; ++c4) {
      float4 av[4], wv4[4];
      #pragma unroll
      for (int r = 0; r < 4; ++r)
        av[r] = *(const float4*)&s_as[ty * 4 + r][half * 64 + c4 * 4];
      #pragma unroll
      for (int cc = 0; cc < 4; ++cc)
        wv4[cc] = *(const float4*)&s_w[(c4 * 4 + cc) * 132 + tx * 4];
      #pragma unroll
      for (int r = 0; r < 4; ++r) {
        float a0 = av[r].x, a1 = av[r].y, a2 = av[r].z, a3 = av[r].w;
        accT[r][0] += a0 * wv4[0].x + a1 * wv4[1].x + a2 * wv4[2].x + a3 * wv4[3].x;
        accT[r][1] += a0 * wv4[0].y + a1 * wv4[1].y + a2 * wv4[2].y + a3 * wv4[3].y;
        accT[r][2] += a0 * wv4[0].z + a1 * wv4[1].z + a2 * wv4[2].z + a3 * wv4[3].z;
        accT[r][3] += a0 * wv4[0].w + a1 * wv4[1].w + a2 * wv4[2].w + a3 * wv4[3].w;
      }
    }
  }
  #pragma unroll
  for (int r = 0; r < 4; ++r) {
    float4 v = make_float4(accT[r][0], accT[r][1], accT[r][2], accT[r][3]);
    *(float4*)&s_T[ty * 4 + r][tx * 4] = v;
  }
  __syncthreads();

  // ---- heads_out ----
  #pragma unroll
  for (int i = 0; i < 8; ++i) {
    int f = i * 256 + t;
    int n = f >> 6, p = f & 63;
    float v = s_xin[n][p] * s_T[n][p] + s_T[n][64 + p];
    ho[((size_t)h * NROWS + n0 + n) * 64 + p] = v;
  }
}

// ---------------------------------------------------------------------------
extern "C" void kernel_launch(void* const* d_in, const int* in_sizes, int n_in,
                              void* d_out, int out_size, void* d_ws, size_t ws_size,
                              hipStream_t stream) {
  const float* x    = (const float*)d_in[0];
  const float* ctrs = (const float*)d_in[1];
  const float* Wv   = (const float*)d_in[2];
  const float* Ov   = (const float*)d_in[3];
  const float* Wq   = (const float*)d_in[4];
  const float* Wo   = (const float*)d_in[5];
  float* out = (float*)d_out;
  float* ws  = (float*)d_ws;

  float* Wqt   = ws;                 // 131072 f
  float* W2    = ws + 131072;        // 131072 f
  float* cb    = ws + 262144;        // 1024 f
  float* xin   = ws + 263168;        // 8192*512 f
  float* ho    = ws + 4457472;       // 8*8192*64 f   (total ~33 MB)

  prep_kernel<<<NH * NC, 64, 0, stream>>>(ctrs, Wv, Ov, W2, cb);
  wqt_kernel<<<512, 256, 0, stream>>>(Wq, Wqt);
  // x_in = x @ Wqt : (8192 x 512), K=256
  gemm_kernel<<<dim3(512 / BN, NROWS / BM), 256, 0, stream>>>(
      x, Wqt, xin, DIN, DIN, 512, 512);
  // fused RBF softmax mixture
  fused_kernel<<<NH * (NROWS / 32), 256, 0, stream>>>(xin, ctrs, cb, W2, ho);
  // out = ho_view(8192x512) @ Wo : (8192 x 256), K=512
  gemm_kernel<<<dim3(DOUT / BN, NROWS / BM), 256, 0, stream>>>(
      ho, Wo, out, 512, 512, DOUT, DOUT);
}

// Round 3
// 72.456 us; speedup vs baseline: 2.8846x; 2.8846x over previous
//
#include <hip/hip_runtime.h>
#include <math.h>

#define NROWS 8192
#define DIN   256
#define NH    8
#define NC    128
#define DOUT  256

typedef unsigned short ushort_t;
typedef __attribute__((ext_vector_type(8))) short bf16x8;
typedef __attribute__((ext_vector_type(4))) float f32x4;
typedef __attribute__((ext_vector_type(4))) unsigned short u16x4;

static __device__ __forceinline__ ushort_t f2bf(float f) {
  union { float f; unsigned u; } v; v.f = f;
  unsigned r = v.u + 0x7fffu + ((v.u >> 16) & 1u);
  return (ushort_t)(r >> 16);
}
static __device__ __forceinline__ float bf2f(ushort_t h) {
  union { unsigned u; float f; } v; v.u = ((unsigned)h) << 16;
  return v.f;
}

#define MFMA16(a, b, c) __builtin_amdgcn_mfma_f32_16x16x32_bf16((a), (b), (c), 0, 0, 0)
#define GLOAD_LDS16(g, l)                                                     \
  __builtin_amdgcn_global_load_lds(                                           \
      (const __attribute__((address_space(1))) void*)(g),                     \
      (__attribute__((address_space(3))) void*)(l), 16, 0, 0)

// ---------------------------------------------------------------------------
// x (f32 [8192][256]) -> xc bf16 [8192][512] = [hi(256) | lo(256)]
// ---------------------------------------------------------------------------
__global__ __launch_bounds__(256) void cvt_x_kernel(
    const float* __restrict__ x, ushort_t* __restrict__ xc) {
  int q = blockIdx.x * 256 + threadIdx.x;      // < 8192*64
  int n = q >> 6, k4 = (q & 63) << 2;
  float4 v = *(const float4*)(x + (size_t)n * 256 + k4);
  float f[4] = {v.x, v.y, v.z, v.w};
  u16x4 hv, lv;
  #pragma unroll
  for (int i = 0; i < 4; ++i) {
    ushort_t hi = f2bf(f[i]);
    hv[i] = hi;
    lv[i] = f2bf(f[i] - bf2f(hi));
  }
  *(u16x4*)(xc + (size_t)n * 512 + k4) = hv;
  *(u16x4*)(xc + (size_t)n * 512 + 256 + k4) = lv;
}

// ---------------------------------------------------------------------------
// Wq (256,64,8) -> wcvtT bf16 [j=h*64+p][768] : rows of B^T, K = [hi|lo|hi]
// ---------------------------------------------------------------------------
__global__ __launch_bounds__(256) void prep_w_kernel(
    const float* __restrict__ Wq, ushort_t* __restrict__ wcvtT) {
  int j = blockIdx.x;    // 0..511
  int k = threadIdx.x;   // 0..255
  int h = j >> 6, p = j & 63;
  float v = Wq[((size_t)k * 64 + p) * 8 + h];
  ushort_t hi = f2bf(v), lo = f2bf(v - bf2f(hi));
  wcvtT[(size_t)j * 768 + k]       = hi;
  wcvtT[(size_t)j * 768 + 256 + k] = lo;
  wcvtT[(size_t)j * 768 + 512 + k] = hi;
}

// ---------------------------------------------------------------------------
// ctrs -> ctr3T bf16 [h*128+c][192] (B^T for logits, K=[hi|lo|hi]) + cbias
// ---------------------------------------------------------------------------
__global__ __launch_bounds__(64) void prep_ctr_kernel(
    const float* __restrict__ ctrs, ushort_t* __restrict__ ctr3T,
    float* __restrict__ cbias) {
  int b = blockIdx.x;    // h*128 + c
  int p = threadIdx.x;   // 0..63
  float v = ctrs[(size_t)b * 64 + p];
  float sq = v * v;
  #pragma unroll
  for (int off = 32; off >= 1; off >>= 1) sq += __shfl_xor(sq, off, 64);
  if (p == 0) cbias[b] = -sq;
  ushort_t hi = f2bf(v), lo = f2bf(v - bf2f(hi));
  ctr3T[(size_t)b * 192 + p]       = hi;
  ctr3T[(size_t)b * 192 + 64 + p]  = lo;
  ctr3T[(size_t)b * 192 + 128 + p] = hi;
}

// ---------------------------------------------------------------------------
// Wv/Ov -> W2bT bf16 [h*128 + n][k=c] : n<64 -> WvSum[c][n], n>=64 -> Ov[c][n-64]
// ---------------------------------------------------------------------------
__global__ __launch_bounds__(64) void prep_w2_kernel(
    const float* __restrict__ Wv, const float* __restrict__ Ov,
    ushort_t* __restrict__ W2bT) {
  int b = blockIdx.x;    // h*128 + c
  int p = threadIdx.x;   // 0..63
  int h = b >> 7, c = b & 127;
  const float* wv = Wv + (size_t)b * 4096;
  float acc = 0.f;
  #pragma unroll 8
  for (int g = 0; g < 64; ++g) acc += wv[g * 64 + p];
  W2bT[((size_t)h * 128 + p) * 128 + c]      = f2bf(acc);
  W2bT[((size_t)h * 128 + 64 + p) * 128 + c] = f2bf(Ov[(size_t)b * 64 + p]);
}

// ---------------------------------------------------------------------------
// Wo (512,256) -> WoT bf16 [n][512]
// ---------------------------------------------------------------------------
__global__ __launch_bounds__(256) void prep_wo_kernel(
    const float* __restrict__ Wo, ushort_t* __restrict__ WoT) {
  int k = blockIdx.x;    // 0..511
  int n = threadIdx.x;   // 0..255
  WoT[(size_t)n * 512 + k] = f2bf(Wo[(size_t)k * 256 + n]);
}

// ---------------------------------------------------------------------------
// MFMA GEMM: C[M x N] = A[M x Klog(phys 512)] * Bt[N x Klog]^T
// BM=128 BN=64 BK=64, 256 threads (4 waves as 2x2, wave tile 64x32).
// SPLIT: logical K 768 -> phys col (k<256 ? k : k-256)  (A = [hi|hi|lo])
// OUTMODE 0: write packed (hi|lo<<16) u32 to out[row*512+col]
// OUTMODE 1: write f32 to out[row*256+col]
// A-tile staged via global_load_lds w/ XOR-swizzled source (slot ^= row&7).
// ---------------------------------------------------------------------------
template <int SPLIT, int OUTMODE>
__global__ __launch_bounds__(256) void mfma_gemm_kernel(
    const ushort_t* __restrict__ A, const ushort_t* __restrict__ Bt,
    void* __restrict__ out, int Klog, int ldb) {
  __shared__ ushort_t At[128 * 64];   // [row][8 slots * 8 bf16], swizzled
  __shared__ ushort_t Bl[64 * 64];
  const int t = threadIdx.x;
  const int w = t >> 6, l = t & 63;
  const int wr = w >> 1, wc = w & 1;
  const int m0 = blockIdx.y * 128, n0 = blockIdx.x * 64;
  const int lr = l & 15, lk = l >> 4;

  f32x4 acc[4][2];
  #pragma unroll
  for (int a = 0; a < 4; ++a)
    #pragma unroll
    for (int b = 0; b < 2; ++b) acc[a][b] = (f32x4){0.f, 0.f, 0.f, 0.f};

  for (int k0 = 0; k0 < Klog; k0 += 64) {
    // stage A: 128x64 bf16 = 1024 x 16B chunks
    #pragma unroll
    for (int i = 0; i < 4; ++i) {
      int q = (i * 4 + w) * 64 + l;
      int row = q >> 3, s = q & 7;
      int klog = k0 + ((s ^ (row & 7)) << 3);
      int kp = SPLIT ? (klog < 256 ? klog : klog - 256) : klog;
      GLOAD_LDS16(A + (size_t)(m0 + row) * 512 + kp,
                  (char*)At + (size_t)(i * 4 + w) * 1024);
    }
    // stage B: 64x64 bf16 = 512 x 16B chunks
    #pragma unroll
    for (int i = 0; i < 2; ++i) {
      int q = (i * 4 + w) * 64 + l;
      int row = q >> 3, s = q & 7;
      int klog = k0 + ((s ^ (row & 7)) << 3);
      GLOAD_LDS16(Bt + (size_t)(n0 + row) * ldb + klog,
                  (char*)Bl + (size_t)(i * 4 + w) * 1024);
    }
    __syncthreads();
    #pragma unroll
    for (int kk = 0; kk < 2; ++kk) {
      bf16x8 af[4], bfr[2];
      #pragma unroll
      for (int a = 0; a < 4; ++a) {
        int row = wr * 64 + a * 16 + lr;
        int s = (kk * 4 + lk) ^ (row & 7);
        af[a] = *(const bf16x8*)((const char*)At + row * 128 + s * 16);
      }
      #pragma unroll
      for (int b = 0; b < 2; ++b) {
        int row = wc * 32 + b * 16 + lr;
        int s = (kk * 4 + lk) ^ (row & 7);
        bfr[b] = *(const bf16x8*)((const char*)Bl + row * 128 + s * 16);
      }
      #pragma unroll
      for (int a = 0; a < 4; ++a)
        #pragma unroll
        for (int b = 0; b < 2; ++b)
          acc[a][b] = MFMA16(af[a], bfr[b], acc[a][b]);
    }
    __syncthreads();
  }
  // epilogue: C element (row=(lane>>4)*4+reg, col=lane&15) per 16x16 frag
  #pragma unroll
  for (int a = 0; a < 4; ++a) {
    #pragma unroll
    for (int b = 0; b < 2; ++b) {
      #pragma unroll
      for (int r = 0; r < 4; ++r) {
        int rowg = m0 + wr * 64 + a * 16 + lk * 4 + r;
        int colg = n0 + wc * 32 + b * 16 + lr;
        float v = acc[a][b][r];
        if (OUTMODE == 0) {
          ushort_t hi = f2bf(v);
          ushort_t lo = f2bf(v - bf2f(hi));
          ((unsigned*)out)[(size_t)rowg * 512 + colg] =
              (unsigned)hi | ((unsigned)lo << 16);
        } else {
          ((float*)out)[(size_t)rowg * 256 + colg] = v;
        }
      }
    }
  }
}

// ---------------------------------------------------------------------------
// Fused: logits (split-bf16 MFMA, K=192) -> in-register softmax ->
//        T = a @ W2 (bf16 MFMA, K=128) -> ho = xin*t1 + t2 -> ho2 bf16
// ho2 is the FLAT (h,N,p) tensor viewed as [8192][512] (reference reshape:
// row-major reinterpretation, row m = h*1024 + n/8, col = (n%8)*64 + p).
// grid = NH * 128 blocks (64 rows each), 256 threads (4 waves, 16 rows/wave)
// ---------------------------------------------------------------------------
__global__ __launch_bounds__(256) void fused_mfma_kernel(
    const unsigned* __restrict__ xincvt,   // [8192][512] packed hi|lo
    const ushort_t* __restrict__ ctr3T,    // [h*128+c][192]
    const float* __restrict__ cbias,       // [h*128+c]
    const ushort_t* __restrict__ W2bT,     // [h*128+n][128]
    ushort_t* __restrict__ ho2) {          // flat (h,N,p)
  __shared__ ushort_t A1[64 * 136];   // xin: cols 0-63 hi, 64-127 lo (pad 8)
  __shared__ ushort_t A2[64 * 136];   // assignments bf16
  __shared__ ushort_t Bt[128 * 40];   // B chunks [row][32+8pad]; reused for ho
  __shared__ float cb_lds[128];

  const int t = threadIdx.x;
  const int w = t >> 6, l = t & 63;
  const int lr = l & 15, lk = l >> 4;
  const int h = blockIdx.x >> 7;
  const int n0 = (blockIdx.x & 127) * 64;

  // stage A1 (unpack packed hi|lo)
  #pragma unroll
  for (int i = 0; i < 4; ++i) {
    int q = i * 256 + t;
    int row = q >> 4, seg = q & 15;
    uint4 v = *(const uint4*)(xincvt + (size_t)(n0 + row) * 512 + h * 64 + seg * 4);
    u16x4 hv = {(ushort_t)(v.x & 0xffff), (ushort_t)(v.y & 0xffff),
                (ushort_t)(v.z & 0xffff), (ushort_t)(v.w & 0xffff)};
    u16x4 lv = {(ushort_t)(v.x >> 16), (ushort_t)(v.y >> 16),
                (ushort_t)(v.z >> 16), (ushort_t)(v.w >> 16)};
    *(u16x4*)&A1[row * 136 + seg * 4] = hv;
    *(u16x4*)&A1[row * 136 + 64 + seg * 4] = lv;
  }
  if (t < 128) cb_lds[t] = cbias[h * 128 + t];

  // ---- logits: rows 16/wave x 128 c, K=192 ----
  f32x4 acc[8];
  #pragma unroll
  for (int cj = 0; cj < 8; ++cj) acc[cj] = (f32x4){0.f, 0.f, 0.f, 0.f};
  for (int ks = 0; ks < 6; ++ks) {
    #pragma unroll
    for (int i = 0; i < 2; ++i) {
      int q = i * 256 + t;
      int row = q >> 2, s = q & 3;
      uint4 v = *(const uint4*)(ctr3T + (size_t)(h * 128 + row) * 192 + ks * 32 + s * 8);
      *(uint4*)((char*)Bt + row * 80 + s * 16) = v;
    }
    __syncthreads();
    int klog = ks * 32 + lk * 8;
    int kp = klog < 64 ? klog : klog - 64;   // A=[hi|hi|lo] x B=[hi|lo|hi]
    bf16x8 af = *(const bf16x8*)&A1[(w * 16 + lr) * 136 + kp];
    #pragma unroll
    for (int cj = 0; cj < 8; ++cj) {
      bf16x8 bfr = *(const bf16x8*)((const char*)Bt + (cj * 16 + lr) * 80 + lk * 16);
      acc[cj] = MFMA16(af, bfr, acc[cj]);
    }
    __syncthreads();
  }

  // ---- softmax (rows fully inside wave: reduce over cj + low-4-bit lanes) ----
  float cbv[8];
  #pragma unroll
  for (int cj = 0; cj < 8; ++cj) cbv[cj] = cb_lds[cj * 16 + lr];
  #pragma unroll
  for (int r = 0; r < 4; ++r) {
    float v[8];
    float m = -1e30f;
    #pragma unroll
    for (int cj = 0; cj < 8; ++cj) {
      v[cj] = 2.f * acc[cj][r] + cbv[cj];
      m = fmaxf(m, v[cj]);
    }
    m = fmaxf(m, __shfl_xor(m, 1, 64));
    m = fmaxf(m, __shfl_xor(m, 2, 64));
    m = fmaxf(m, __shfl_xor(m, 4, 64));
    m = fmaxf(m, __shfl_xor(m, 8, 64));
    float s = 0.f;
    #pragma unroll
    for (int cj = 0; cj < 8; ++cj) {
      v[cj] = __expf(v[cj] - m);
      s += v[cj];
    }
    s += __shfl_xor(s, 1, 64);
    s += __shfl_xor(s, 2, 64);
    s += __shfl_xor(s, 4, 64);
    s += __shfl_xor(s, 8, 64);
    float inv = 1.f / s;
    int row = w * 16 + lk * 4 + r;
    #pragma unroll
    for (int cj = 0; cj < 8; ++cj)
      A2[row * 136 + cj * 16 + lr] = f2bf(v[cj] * inv);
  }

  // ---- T = assignments @ W2 : rows 16/wave x 128 (t1|t2), K=128 ----
  f32x4 accT[8];
  #pragma unroll
  for (int cj = 0; cj < 8; ++cj) accT[cj] = (f32x4){0.f, 0.f, 0.f, 0.f};
  for (int ks = 0; ks < 4; ++ks) {
    #pragma unroll
    for (int i = 0; i < 2; ++i) {
      int q = i * 256 + t;
      int row = q >> 2, s = q & 3;
      uint4 v = *(const uint4*)(W2bT + (size_t)(h * 128 + row) * 128 + ks * 32 + s * 8);
      *(uint4*)((char*)Bt + row * 80 + s * 16) = v;
    }
    __syncthreads();
    bf16x8 af = *(const bf16x8*)&A2[(w * 16 + lr) * 136 + ks * 32 + lk * 8];
    #pragma unroll
    for (int cj = 0; cj < 8; ++cj) {
      bf16x8 bfr = *(const bf16x8*)((const char*)Bt + (cj * 16 + lr) * 80 + lk * 16);
      accT[cj] = MFMA16(af, bfr, accT[cj]);
    }
    __syncthreads();
  }

  // ---- epilogue: ho = xin*t1 + t2 ; bounce via Bt as [64][64] bf16 ----
  #pragma unroll
  for (int cj = 0; cj < 4; ++cj) {
    #pragma unroll
    for (int r = 0; r < 4; ++r) {
      int row = w * 16 + lk * 4 + r;
      int p = cj * 16 + lr;
      float xin = bf2f(A1[row * 136 + p]) + bf2f(A1[row * 136 + 64 + p]);
      float hov = xin * accT[cj][r] + accT[cj + 4][r];
      ((ushort_t*)Bt)[row * 64 + p] = f2bf(hov);
    }
  }
  __syncthreads();
  // write FLAT (h,N,p): element (h, n0+row, p) at ho2[(h*8192 + n0+row)*64 + p]
  #pragma unroll
  for (int i = 0; i < 2; ++i) {
    int q = i * 256 + t;
    int row = q >> 3, s = q & 7;
    uint4 v = *(const uint4*)((const char*)Bt + row * 128 + s * 16);
    *(uint4*)(ho2 + ((size_t)h * NROWS + n0 + row) * 64 + s * 8) = v;
  }
}

// ---------------------------------------------------------------------------
extern "C" void kernel_launch(void* const* d_in, const int* in_sizes, int n_in,
                              void* d_out, int out_size, void* d_ws, size_t ws_size,
                              hipStream_t stream) {
  (void)in_sizes; (void)n_in; (void)out_size; (void)ws_size;
  const float* x    = (const float*)d_in[0];
  const float* ctrs = (const float*)d_in[1];
  const float* Wv   = (const float*)d_in[2];
  const float* Ov   = (const float*)d_in[3];
  const float* Wq   = (const float*)d_in[4];
  const float* Wo   = (const float*)d_in[5];
  float* out = (float*)d_out;

  char* wsb = (char*)d_ws;
  ushort_t* xc    = (ushort_t*)wsb;                   // 8 MB  [8192][512]
  ushort_t* ho2   = xc;                               // aliased (xc dead after gemm1)
  ushort_t* wcvtT = (ushort_t*)(wsb + 8388608);       // 768 KB
  ushort_t* ctr3T = (ushort_t*)(wsb + 9175040);       // 384 KB
  float*    cb    = (float*)   (wsb + 9568256);       // 4 KB
  ushort_t* W2bT  = (ushort_t*)(wsb + 9572352);       // 256 KB
  ushort_t* WoT   = (ushort_t*)(wsb + 9834496);       // 256 KB
  unsigned* xincvt= (unsigned*)(wsb + 10096640);      // 16 MB [8192][512]

  cvt_x_kernel<<<2048, 256, 0, stream>>>(x, xc);
  prep_w_kernel<<<512, 256, 0, stream>>>(Wq, wcvtT);
  prep_ctr_kernel<<<1024, 64, 0, stream>>>(ctrs, ctr3T, cb);
  prep_w2_kernel<<<1024, 64, 0, stream>>>(Wv, Ov, W2bT);
  prep_wo_kernel<<<512, 256, 0, stream>>>(Wo, WoT);

  // xin = x @ Wq (split-bf16, Klog=768) -> packed hi|lo
  mfma_gemm_kernel<1, 0><<<dim3(8, 64), 256, 0, stream>>>(xc, wcvtT, xincvt, 768, 768);
  // RBF softmax mixture -> ho2 flat (h,N,p)
  fused_mfma_kernel<<<NH * 128, 256, 0, stream>>>(xincvt, ctr3T, cb, W2bT, ho2);
  // out = ho2_view(8192x512) @ Wo (bf16, Klog=512)
  mfma_gemm_kernel<0, 1><<<dim3(4, 64), 256, 0, stream>>>(ho2, WoT, out, 512, 512);
}

// Round 6
// 65.565 us; speedup vs baseline: 3.1878x; 1.1051x over previous
//
#include <hip/hip_runtime.h>
#include <math.h>

#define NROWS 8192
#define DIN   256
#define NH    8
#define NC    128
#define DOUT  256

typedef unsigned short ushort_t;
typedef __attribute__((ext_vector_type(8))) short bf16x8;
typedef __attribute__((ext_vector_type(4))) float f32x4;
typedef __attribute__((ext_vector_type(4))) unsigned short u16x4;

static __device__ __forceinline__ ushort_t f2bf(float f) {
  union { float f; unsigned u; } v; v.f = f;
  unsigned r = v.u + 0x7fffu + ((v.u >> 16) & 1u);
  return (ushort_t)(r >> 16);
}
static __device__ __forceinline__ float bf2f(ushort_t h) {
  union { unsigned u; float f; } v; v.u = ((unsigned)h) << 16;
  return v.f;
}

#define MFMA16(a, b, c) __builtin_amdgcn_mfma_f32_16x16x32_bf16((a), (b), (c), 0, 0, 0)
#define GLOAD_LDS16(g, l)                                                     \
  __builtin_amdgcn_global_load_lds(                                           \
      (const __attribute__((address_space(1))) void*)(g),                     \
      (__attribute__((address_space(3))) void*)(l), 16, 0, 0)

// ---------------------------------------------------------------------------
// x (f32 [8192][256]) -> xc bf16 [8192][512] = [hi(256) | lo(256)]
// ---------------------------------------------------------------------------
__global__ __launch_bounds__(256) void cvt_x_kernel(
    const float* __restrict__ x, ushort_t* __restrict__ xc) {
  int q = blockIdx.x * 256 + threadIdx.x;      // < 8192*64
  int n = q >> 6, k4 = (q & 63) << 2;
  float4 v = *(const float4*)(x + (size_t)n * 256 + k4);
  float f[4] = {v.x, v.y, v.z, v.w};
  u16x4 hv, lv;
  #pragma unroll
  for (int i = 0; i < 4; ++i) {
    ushort_t hi = f2bf(f[i]);
    hv[i] = hi;
    lv[i] = f2bf(f[i] - bf2f(hi));
  }
  *(u16x4*)(xc + (size_t)n * 512 + k4) = hv;
  *(u16x4*)(xc + (size_t)n * 512 + 256 + k4) = lv;
}

// ---------------------------------------------------------------------------
// Merged light prep (grid 1280 x 256):
//  blocks [0,512):    Wq (256,64,8) -> wcvtT [j=h*64+p][768], K=[hi|lo|hi]
//  blocks [512,768):  ctrs -> ctr3T [h*128+c][192] (K=[hi|lo|hi]) + cbias
//  blocks [768,1280): Wo (512,256) -> WoT [n][512]
// ---------------------------------------------------------------------------
__global__ __launch_bounds__(256) void prep_light_kernel(
    const float* __restrict__ Wq, const float* __restrict__ ctrs,
    const float* __restrict__ Wo, ushort_t* __restrict__ wcvtT,
    ushort_t* __restrict__ ctr3T, float* __restrict__ cbias,
    ushort_t* __restrict__ WoT) {
  int bid = blockIdx.x;
  int t = threadIdx.x;
  if (bid < 512) {
    int j = bid, k = t;
    int h = j >> 6, p = j & 63;
    float v = Wq[((size_t)k * 64 + p) * 8 + h];
    ushort_t hi = f2bf(v), lo = f2bf(v - bf2f(hi));
    wcvtT[(size_t)j * 768 + k]       = hi;
    wcvtT[(size_t)j * 768 + 256 + k] = lo;
    wcvtT[(size_t)j * 768 + 512 + k] = hi;
  } else if (bid < 768) {
    int idx = (bid - 512) * 4 + (t >> 6);   // h*128+c
    int p = t & 63;
    float v = ctrs[(size_t)idx * 64 + p];
    float sq = v * v;
    #pragma unroll
    for (int off = 32; off >= 1; off >>= 1) sq += __shfl_xor(sq, off, 64);
    if (p == 0) cbias[idx] = -sq;
    ushort_t hi = f2bf(v), lo = f2bf(v - bf2f(hi));
    ctr3T[(size_t)idx * 192 + p]       = hi;
    ctr3T[(size_t)idx * 192 + 64 + p]  = lo;
    ctr3T[(size_t)idx * 192 + 128 + p] = hi;
  } else {
    int k = bid - 768;    // 0..511
    int n = t;            // 0..255
    WoT[(size_t)n * 512 + k] = f2bf(Wo[(size_t)k * 256 + n]);
  }
}

// ---------------------------------------------------------------------------
// Wv/Ov -> W2bT bf16 [h*128 + n][k=c] : n<64 -> WvSum[c][n], n>=64 -> Ov[c][n-64]
// ---------------------------------------------------------------------------
__global__ __launch_bounds__(64) void prep_w2_kernel(
    const float* __restrict__ Wv, const float* __restrict__ Ov,
    ushort_t* __restrict__ W2bT) {
  int b = blockIdx.x;    // h*128 + c
  int p = threadIdx.x;   // 0..63
  int h = b >> 7, c = b & 127;
  const float* wv = Wv + (size_t)b * 4096;
  float acc = 0.f;
  #pragma unroll 8
  for (int g = 0; g < 64; ++g) acc += wv[g * 64 + p];
  W2bT[((size_t)h * 128 + p) * 128 + c]      = f2bf(acc);
  W2bT[((size_t)h * 128 + 64 + p) * 128 + c] = f2bf(Ov[(size_t)b * 64 + p]);
}

// ---------------------------------------------------------------------------
// MFMA GEMM: C[M x N] = A[M x Klog(phys 512)] * Bt[N x Klog]^T
// BM=128 BN=64 BK=64, 256 threads (4 waves as 2x2, wave tile 64x32).
// SPLIT: logical K 768 -> phys col (k<256 ? k : k-256)  (A = [hi|hi|lo])
// OUTMODE 0: write packed (hi|lo<<16) u32 to out[row*512+col]
// OUTMODE 1: write f32 to out[row*256+col]
// ---------------------------------------------------------------------------
template <int SPLIT, int OUTMODE>
__global__ __launch_bounds__(256) void mfma_gemm_kernel(
    const ushort_t* __restrict__ A, const ushort_t* __restrict__ Bt,
    void* __restrict__ out, int Klog, int ldb) {
  __shared__ ushort_t At[128 * 64];   // [row][8 slots * 8 bf16], swizzled
  __shared__ ushort_t Bl[64 * 64];
  const int t = threadIdx.x;
  const int w = t >> 6, l = t & 63;
  const int wr = w >> 1, wc = w & 1;
  const int m0 = blockIdx.y * 128, n0 = blockIdx.x * 64;
  const int lr = l & 15, lk = l >> 4;

  f32x4 acc[4][2];
  #pragma unroll
  for (int a = 0; a < 4; ++a)
    #pragma unroll
    for (int b = 0; b < 2; ++b) acc[a][b] = (f32x4){0.f, 0.f, 0.f, 0.f};

  for (int k0 = 0; k0 < Klog; k0 += 64) {
    #pragma unroll
    for (int i = 0; i < 4; ++i) {
      int q = (i * 4 + w) * 64 + l;
      int row = q >> 3, s = q & 7;
      int klog = k0 + ((s ^ (row & 7)) << 3);
      int kp = SPLIT ? (klog < 256 ? klog : klog - 256) : klog;
      GLOAD_LDS16(A + (size_t)(m0 + row) * 512 + kp,
                  (char*)At + (size_t)(i * 4 + w) * 1024);
    }
    #pragma unroll
    for (int i = 0; i < 2; ++i) {
      int q = (i * 4 + w) * 64 + l;
      int row = q >> 3, s = q & 7;
      int klog = k0 + ((s ^ (row & 7)) << 3);
      GLOAD_LDS16(Bt + (size_t)(n0 + row) * ldb + klog,
                  (char*)Bl + (size_t)(i * 4 + w) * 1024);
    }
    __syncthreads();
    #pragma unroll
    for (int kk = 0; kk < 2; ++kk) {
      bf16x8 af[4], bfr[2];
      #pragma unroll
      for (int a = 0; a < 4; ++a) {
        int row = wr * 64 + a * 16 + lr;
        int s = (kk * 4 + lk) ^ (row & 7);
        af[a] = *(const bf16x8*)((const char*)At + row * 128 + s * 16);
      }
      #pragma unroll
      for (int b = 0; b < 2; ++b) {
        int row = wc * 32 + b * 16 + lr;
        int s = (kk * 4 + lk) ^ (row & 7);
        bfr[b] = *(const bf16x8*)((const char*)Bl + row * 128 + s * 16);
      }
      #pragma unroll
      for (int a = 0; a < 4; ++a)
        #pragma unroll
        for (int b = 0; b < 2; ++b)
          acc[a][b] = MFMA16(af[a], bfr[b], acc[a][b]);
    }
    __syncthreads();
  }
  #pragma unroll
  for (int a = 0; a < 4; ++a) {
    #pragma unroll
    for (int b = 0; b < 2; ++b) {
      #pragma unroll
      for (int r = 0; r < 4; ++r) {
        int rowg = m0 + wr * 64 + a * 16 + lk * 4 + r;
        int colg = n0 + wc * 32 + b * 16 + lr;
        float v = acc[a][b][r];
        if (OUTMODE == 0) {
          ushort_t hi = f2bf(v);
          ushort_t lo = f2bf(v - bf2f(hi));
          ((unsigned*)out)[(size_t)rowg * 512 + colg] =
              (unsigned)hi | ((unsigned)lo << 16);
        } else {
          ((float*)out)[(size_t)rowg * 256 + colg] = v;
        }
      }
    }
  }
}

// ---------------------------------------------------------------------------
// Fused v2h (hardened): logits (split-bf16 MFMA, K=192) -> in-reg softmax ->
//           T = a @ W2 (bf16 MFMA, K=128) -> ho = xin*t1 + t2 -> FLAT (h,N,p)
// Sync discipline: every buffer-consumption entry = {wait own vmcnt(N);
// barrier; sched_barrier}; every barrier preceding a buffer overwrite is
// preceded by {lgkmcnt(0) drain; sched_barrier} so no wave's ds_reads are
// outstanding when another wave's DMA overwrites the buffer.
// ---------------------------------------------------------------------------
__global__ __launch_bounds__(256) void fused_mfma_kernel(
    const unsigned* __restrict__ xincvt,   // [8192][512] packed hi|lo
    const ushort_t* __restrict__ ctr3T,    // [h*128+c][192]
    const float* __restrict__ cbias,       // [h*128+c]
    const ushort_t* __restrict__ W2bT,     // [h*128+n][128]
    ushort_t* __restrict__ ho2) {          // flat (h,N,p)
  __shared__ ushort_t A1[64 * 136];   // xin: cols 0-63 hi, 64-127 lo (pad 8)
  __shared__ ushort_t A2[64 * 136];   // assignments bf16
  __shared__ char Blds[2][16384];     // B buf: [128 rows][8 slots][16B], swz
  __shared__ float cb_lds[128];

  const int t = threadIdx.x;
  const int w = t >> 6, l = t & 63;
  const int lr = l & 15, lk = l >> 4;
  const int h = blockIdx.x >> 7;
  const int n0 = (blockIdx.x & 127) * 64;

#define STAGE_B(BUF, SRC, LDB, KOFF)                                          \
  {                                                                           \
    _Pragma("unroll")                                                         \
    for (int i = 0; i < 4; ++i) {                                             \
      int q = (i * 4 + w) * 64 + l;                                           \
      int row = q >> 3, s = q & 7;                                            \
      GLOAD_LDS16((SRC) + (size_t)(h * 128 + row) * (LDB) + (KOFF) +          \
                      ((s ^ (row & 7)) << 3),                                 \
                  (char*)(BUF) + (size_t)(i * 4 + w) * 1024);                 \
    }                                                                         \
  }

#define MFMA_STEP(BUF, ACC, ALDS, KBASE, ASPLIT)                              \
  {                                                                           \
    _Pragma("unroll")                                                         \
    for (int kk = 0; kk < 2; ++kk) {                                          \
      int klog = (KBASE) + kk * 32 + lk * 8;                                  \
      int kp = (ASPLIT) ? (klog < 64 ? klog : klog - 64) : klog;              \
      bf16x8 af = *(const bf16x8*)&(ALDS)[(w * 16 + lr) * 136 + kp];          \
      _Pragma("unroll")                                                       \
      for (int cj = 0; cj < 8; ++cj) {                                        \
        int brow = cj * 16 + lr;                                              \
        int slot = (kk * 4 + lk) ^ (brow & 7);                                \
        bf16x8 bfr =                                                          \
            *(const bf16x8*)((const char*)(BUF) + brow * 128 + slot * 16);    \
        (ACC)[cj] = MFMA16(af, bfr, (ACC)[cj]);                               \
      }                                                                       \
    }                                                                         \
  }

#define BAR() __builtin_amdgcn_s_barrier()
#define SCHED() __builtin_amdgcn_sched_barrier(0)
#define DRAIN_LGKM()                                                          \
  { asm volatile("s_waitcnt lgkmcnt(0)" ::: "memory"); SCHED(); }

  // issue B prologue stages (DMA, overlaps with A1 staging below)
  STAGE_B(Blds[0], ctr3T, 192, 0);
  STAGE_B(Blds[1], ctr3T, 192, 64);

  // stage A1 (unpack packed hi|lo)
  #pragma unroll
  for (int i = 0; i < 4; ++i) {
    int q = i * 256 + t;
    int row = q >> 4, seg = q & 15;
    uint4 v = *(const uint4*)(xincvt + (size_t)(n0 + row) * 512 + h * 64 + seg * 4);
    u16x4 hv = {(ushort_t)(v.x & 0xffff), (ushort_t)(v.y & 0xffff),
                (ushort_t)(v.z & 0xffff), (ushort_t)(v.w & 0xffff)};
    u16x4 lv = {(ushort_t)(v.x >> 16), (ushort_t)(v.y >> 16),
                (ushort_t)(v.z >> 16), (ushort_t)(v.w >> 16)};
    *(u16x4*)&A1[row * 136 + seg * 4] = hv;
    *(u16x4*)&A1[row * 136 + 64 + seg * 4] = lv;
  }
  if (t < 128) cb_lds[t] = cbias[h * 128 + t];

  f32x4 acc[8];
  #pragma unroll
  for (int cj = 0; cj < 8; ++cj) acc[cj] = (f32x4){0.f, 0.f, 0.f, 0.f};

  // step 0 (logits k 0..63) — reads Blds[0]
  asm volatile("s_waitcnt vmcnt(4) lgkmcnt(0)" ::: "memory");
  BAR(); SCHED();
  MFMA_STEP(Blds[0], acc, A1, 0, 1);
  DRAIN_LGKM();
  BAR(); SCHED();
  // step 1 (logits k 64..127) — reads Blds[1]; restages Blds[0]
  STAGE_B(Blds[0], ctr3T, 192, 128);
  asm volatile("s_waitcnt vmcnt(4)" ::: "memory");
  BAR(); SCHED();
  MFMA_STEP(Blds[1], acc, A1, 64, 1);
  DRAIN_LGKM();
  BAR(); SCHED();
  // step 2 (logits k 128..191) — reads Blds[0]; restages Blds[1]
  STAGE_B(Blds[1], W2bT, 128, 0);
  asm volatile("s_waitcnt vmcnt(4)" ::: "memory");
  BAR(); SCHED();
  MFMA_STEP(Blds[0], acc, A1, 128, 1);

  // ---- softmax (rows fully inside wave; A2 rows are own-wave) ----
  {
    float cbv[8];
    #pragma unroll
    for (int cj = 0; cj < 8; ++cj) cbv[cj] = cb_lds[cj * 16 + lr];
    #pragma unroll
    for (int r = 0; r < 4; ++r) {
      float v[8];
      float m = -1e30f;
      #pragma unroll
      for (int cj = 0; cj < 8; ++cj) {
        v[cj] = 2.f * acc[cj][r] + cbv[cj];
        m = fmaxf(m, v[cj]);
      }
      m = fmaxf(m, __shfl_xor(m, 1, 64));
      m = fmaxf(m, __shfl_xor(m, 2, 64));
      m = fmaxf(m, __shfl_xor(m, 4, 64));
      m = fmaxf(m, __shfl_xor(m, 8, 64));
      float s = 0.f;
      #pragma unroll
      for (int cj = 0; cj < 8; ++cj) {
        v[cj] = __expf(v[cj] - m);
        s += v[cj];
      }
      s += __shfl_xor(s, 1, 64);
      s += __shfl_xor(s, 2, 64);
      s += __shfl_xor(s, 4, 64);
      s += __shfl_xor(s, 8, 64);
      float inv = 1.f / s;
      int row = w * 16 + lk * 4 + r;
      #pragma unroll
      for (int cj = 0; cj < 8; ++cj)
        A2[row * 136 + cj * 16 + lr] = f2bf(v[cj] * inv);
    }
  }
  DRAIN_LGKM();          // step-2 ds_reads + A2 writes drained
  BAR(); SCHED();        // now safe to overwrite Blds[0]

  f32x4 accT[8];
  #pragma unroll
  for (int cj = 0; cj < 8; ++cj) accT[cj] = (f32x4){0.f, 0.f, 0.f, 0.f};

  // step 3 (T k 0..63) — reads Blds[1]; restages Blds[0]
  STAGE_B(Blds[0], W2bT, 128, 64);
  asm volatile("s_waitcnt vmcnt(4)" ::: "memory");
  BAR(); SCHED();
  MFMA_STEP(Blds[1], accT, A2, 0, 0);
  DRAIN_LGKM();
  // step 4 (T k 64..127) — reads Blds[0]: wait own DMAs, THEN barrier
  asm volatile("s_waitcnt vmcnt(0)" ::: "memory");
  BAR(); SCHED();
  MFMA_STEP(Blds[0], accT, A2, 64, 0);

  // ---- epilogue: ho = xin*t1 + t2 ; bounce via Blds[1] as [64][64] bf16 ----
  #pragma unroll
  for (int cj = 0; cj < 4; ++cj) {
    #pragma unroll
    for (int r = 0; r < 4; ++r) {
      int row = w * 16 + lk * 4 + r;
      int p = cj * 16 + lr;
      float xin = bf2f(A1[row * 136 + p]) + bf2f(A1[row * 136 + 64 + p]);
      float hov = xin * accT[cj][r] + accT[cj + 4][r];
      ((ushort_t*)Blds[1])[row * 64 + p] = f2bf(hov);
    }
  }
  DRAIN_LGKM();
  BAR(); SCHED();
  // write FLAT (h,N,p): element (h, n0+row, p) at ho2[(h*8192 + n0+row)*64 + p]
  #pragma unroll
  for (int i = 0; i < 2; ++i) {
    int q = i * 256 + t;
    int row = q >> 3, s = q & 7;
    uint4 v = *(const uint4*)((const char*)Blds[1] + row * 128 + s * 16);
    *(uint4*)(ho2 + ((size_t)h * NROWS + n0 + row) * 64 + s * 8) = v;
  }
#undef STAGE_B
#undef MFMA_STEP
#undef BAR
#undef SCHED
#undef DRAIN_LGKM
}

// ---------------------------------------------------------------------------
extern "C" void kernel_launch(void* const* d_in, const int* in_sizes, int n_in,
                              void* d_out, int out_size, void* d_ws, size_t ws_size,
                              hipStream_t stream) {
  (void)in_sizes; (void)n_in; (void)out_size; (void)ws_size;
  const float* x    = (const float*)d_in[0];
  const float* ctrs = (const float*)d_in[1];
  const float* Wv   = (const float*)d_in[2];
  const float* Ov   = (const float*)d_in[3];
  const float* Wq   = (const float*)d_in[4];
  const float* Wo   = (const float*)d_in[5];
  float* out = (float*)d_out;

  char* wsb = (char*)d_ws;
  ushort_t* xc    = (ushort_t*)wsb;                   // 8 MB  [8192][512]
  ushort_t* ho2   = xc;                               // aliased (xc dead after gemm1)
  ushort_t* wcvtT = (ushort_t*)(wsb + 8388608);       // 768 KB
  ushort_t* ctr3T = (ushort_t*)(wsb + 9175040);       // 384 KB
  float*    cb    = (float*)   (wsb + 9568256);       // 4 KB
  ushort_t* W2bT  = (ushort_t*)(wsb + 9572352);       // 256 KB
  ushort_t* WoT   = (ushort_t*)(wsb + 9834496);       // 256 KB
  unsigned* xincvt= (unsigned*)(wsb + 10096640);      // 16 MB [8192][512]

  cvt_x_kernel<<<2048, 256, 0, stream>>>(x, xc);
  prep_light_kernel<<<1280, 256, 0, stream>>>(Wq, ctrs, Wo, wcvtT, ctr3T, cb, WoT);
  prep_w2_kernel<<<1024, 64, 0, stream>>>(Wv, Ov, W2bT);

  // xin = x @ Wq (split-bf16, Klog=768) -> packed hi|lo
  mfma_gemm_kernel<1, 0><<<dim3(8, 64), 256, 0, stream>>>(xc, wcvtT, xincvt, 768, 768);
  // RBF softmax mixture -> ho2 flat (h,N,p)
  fused_mfma_kernel<<<NH * 128, 256, 0, stream>>>(xincvt, ctr3T, cb, W2bT, ho2);
  // out = ho2_view(8192x512) @ Wo (bf16, Klog=512)
  mfma_gemm_kernel<0, 1><<<dim3(4, 64), 256, 0, stream>>>(ho2, WoT, out, 512, 512);
}

// Round 8
// 50.286 us; speedup vs baseline: 4.1564x; 1.3038x over previous
//
#include <hip/hip_runtime.h>
#include <math.h>

#define NROWS 8192
#define DIN   256
#define NH    8
#define NC    128
#define DOUT  256

typedef unsigned short ushort_t;
typedef __attribute__((ext_vector_type(8))) short bf16x8;
typedef __attribute__((ext_vector_type(4))) float f32x4;
typedef __attribute__((ext_vector_type(8))) unsigned short u16x8;

static __device__ __forceinline__ ushort_t f2bf(float f) {
  union { float f; unsigned u; } v; v.f = f;
  unsigned r = v.u + 0x7fffu + ((v.u >> 16) & 1u);
  return (ushort_t)(r >> 16);
}
static __device__ __forceinline__ float bf2f(ushort_t h) {
  union { unsigned u; float f; } v; v.u = ((unsigned)h) << 16;
  return v.f;
}

#define MFMA16(a, b, c) __builtin_amdgcn_mfma_f32_16x16x32_bf16((a), (b), (c), 0, 0, 0)
#define GLOAD_LDS16(g, l)                                                     \
  __builtin_amdgcn_global_load_lds(                                           \
      (const __attribute__((address_space(1))) void*)(g),                     \
      (__attribute__((address_space(3))) void*)(l), 16, 0, 0)

// ---------------------------------------------------------------------------
// Merged prep (grid 1536 x 256):
//  [0,512):    Wq (256,64,8) -> wcvtT [j=h*64+p][512] = [hi(256)|lo(256)]
//  [512,768):  ctrs -> ctr3T [h*128+c][192] (K=[hi|lo|hi]) + cbias
//  [768,1280): Wo (512,256) -> WoT [n][512]
//  [1280,1536): Wv/Ov -> W2bT [h*128+n][128]
// ---------------------------------------------------------------------------
__global__ __launch_bounds__(256) void prep_kernel(
    const float* __restrict__ Wq, const float* __restrict__ ctrs,
    const float* __restrict__ Wo, const float* __restrict__ Wv,
    const float* __restrict__ Ov, ushort_t* __restrict__ wcvtT,
    ushort_t* __restrict__ ctr3T, float* __restrict__ cbias,
    ushort_t* __restrict__ WoT, ushort_t* __restrict__ W2bT) {
  int bid = blockIdx.x;
  int t = threadIdx.x;
  if (bid < 512) {
    int j = bid, k = t;
    int h = j >> 6, p = j & 63;
    float v = Wq[((size_t)k * 64 + p) * 8 + h];
    ushort_t hi = f2bf(v), lo = f2bf(v - bf2f(hi));
    wcvtT[(size_t)j * 512 + k]       = hi;
    wcvtT[(size_t)j * 512 + 256 + k] = lo;
  } else if (bid < 768) {
    int idx = (bid - 512) * 4 + (t >> 6);   // h*128+c
    int p = t & 63;
    float v = ctrs[(size_t)idx * 64 + p];
    float sq = v * v;
    #pragma unroll
    for (int off = 32; off >= 1; off >>= 1) sq += __shfl_xor(sq, off, 64);
    if (p == 0) cbias[idx] = -sq;
    ushort_t hi = f2bf(v), lo = f2bf(v - bf2f(hi));
    ctr3T[(size_t)idx * 192 + p]       = hi;
    ctr3T[(size_t)idx * 192 + 64 + p]  = lo;
    ctr3T[(size_t)idx * 192 + 128 + p] = hi;
  } else if (bid < 1280) {
    int k = bid - 768;    // 0..511
    int n = t;            // 0..255
    WoT[(size_t)n * 512 + k] = f2bf(Wo[(size_t)k * 256 + n]);
  } else {
    int b = (bid - 1280) * 4 + (t >> 6);   // h*128 + c, 0..1023
    int p = t & 63;
    int h = b >> 7, c = b & 127;
    const float* wv = Wv + (size_t)b * 4096;
    float acc = 0.f;
    #pragma unroll 8
    for (int g = 0; g < 64; ++g) acc += wv[g * 64 + p];
    W2bT[((size_t)h * 128 + p) * 128 + c]      = f2bf(acc);
    W2bT[((size_t)h * 128 + 64 + p) * 128 + c] = f2bf(Ov[(size_t)b * 64 + p]);
  }
}

// ---------------------------------------------------------------------------
// MFMA GEMM (gemm2 only): C[M x N] = A[M x K] * Bt[N x K]^T
// BM=128 BN=64 BK=64, 256 threads (4 waves as 2x2, wave tile 64x32).
// ---------------------------------------------------------------------------
template <int SPLIT, int OUTMODE>
__global__ __launch_bounds__(256) void mfma_gemm_kernel(
    const ushort_t* __restrict__ A, const ushort_t* __restrict__ Bt,
    void* __restrict__ out, int Klog, int ldb) {
  __shared__ ushort_t At[128 * 64];
  __shared__ ushort_t Bl[64 * 64];
  const int t = threadIdx.x;
  const int w = t >> 6, l = t & 63;
  const int wr = w >> 1, wc = w & 1;
  const int m0 = blockIdx.y * 128, n0 = blockIdx.x * 64;
  const int lr = l & 15, lk = l >> 4;

  f32x4 acc[4][2];
  #pragma unroll
  for (int a = 0; a < 4; ++a)
    #pragma unroll
    for (int b = 0; b < 2; ++b) acc[a][b] = (f32x4){0.f, 0.f, 0.f, 0.f};

  for (int k0 = 0; k0 < Klog; k0 += 64) {
    #pragma unroll
    for (int i = 0; i < 4; ++i) {
      int q = (i * 4 + w) * 64 + l;
      int row = q >> 3, s = q & 7;
      int klog = k0 + ((s ^ (row & 7)) << 3);
      int kp = SPLIT ? (klog < 256 ? klog : klog - 256) : klog;
      GLOAD_LDS16(A + (size_t)(m0 + row) * 512 + kp,
                  (char*)At + (size_t)(i * 4 + w) * 1024);
    }
    #pragma unroll
    for (int i = 0; i < 2; ++i) {
      int q = (i * 4 + w) * 64 + l;
      int row = q >> 3, s = q & 7;
      int klog = k0 + ((s ^ (row & 7)) << 3);
      GLOAD_LDS16(Bt + (size_t)(n0 + row) * ldb + klog,
                  (char*)Bl + (size_t)(i * 4 + w) * 1024);
    }
    __syncthreads();
    #pragma unroll
    for (int kk = 0; kk < 2; ++kk) {
      bf16x8 af[4], bfr[2];
      #pragma unroll
      for (int a = 0; a < 4; ++a) {
        int row = wr * 64 + a * 16 + lr;
        int s = (kk * 4 + lk) ^ (row & 7);
        af[a] = *(const bf16x8*)((const char*)At + row * 128 + s * 16);
      }
      #pragma unroll
      for (int b = 0; b < 2; ++b) {
        int row = wc * 32 + b * 16 + lr;
        int s = (kk * 4 + lk) ^ (row & 7);
        bfr[b] = *(const bf16x8*)((const char*)Bl + row * 128 + s * 16);
      }
      #pragma unroll
      for (int a = 0; a < 4; ++a)
        #pragma unroll
        for (int b = 0; b < 2; ++b)
          acc[a][b] = MFMA16(af[a], bfr[b], acc[a][b]);
    }
    __syncthreads();
  }
  #pragma unroll
  for (int a = 0; a < 4; ++a) {
    #pragma unroll
    for (int b = 0; b < 2; ++b) {
      #pragma unroll
      for (int r = 0; r < 4; ++r) {
        int rowg = m0 + wr * 64 + a * 16 + lk * 4 + r;
        int colg = n0 + wc * 32 + b * 16 + lr;
        float v = acc[a][b][r];
        if (OUTMODE == 0) {
          ushort_t hi = f2bf(v);
          ushort_t lo = f2bf(v - bf2f(hi));
          ((unsigned*)out)[(size_t)rowg * 512 + colg] =
              (unsigned)hi | ((unsigned)lo << 16);
        } else {
          ((float*)out)[(size_t)rowg * 256 + colg] = v;
        }
      }
    }
  }
}

// ---------------------------------------------------------------------------
// Fused-all: xin = x@Wq (split-bf16 MFMA, 4 chunks of 64 logical K) ->
//   logits (split-bf16 MFMA, K=192) -> in-reg softmax ->
//   T = a@W2 (bf16 MFMA, K=128) -> ho = xin*t1 + t2 (xin in f32 regs) ->
//   FLAT (h,N,p) bf16 write.
// grid = NH*128 blocks (head h, 64 tokens), 256 threads (4 waves).
// Sync: verified v2h discipline. xin phase: B(kc) DMA force-drained by the
// compiler's wait for x(kc) register loads (issued after B(kc) in the VMEM
// queue; order pinned by sched_barrier).
// ---------------------------------------------------------------------------
__global__ __launch_bounds__(256, 2) void fused_all_kernel(
    const float* __restrict__ x,          // [8192][256] f32
    const ushort_t* __restrict__ wcvtT,   // [512][512] hi|lo
    const ushort_t* __restrict__ ctr3T,   // [1024][192]
    const float* __restrict__ cbias,      // [1024]
    const ushort_t* __restrict__ W2bT,    // [1024][128]
    ushort_t* __restrict__ ho2) {         // flat (h,N,p)
  __shared__ ushort_t A1[64 * 136];             // xin hi|lo bf16 (logits A)
  __shared__ __align__(16) char A2u_raw[18432]; // union: Axh[64][72]+Axl | A2[64][136]
  __shared__ char Blds[2][16384];               // B buf: [128 rows][8 slots][16B]
  __shared__ float cb_lds[128];

  ushort_t* Axh = (ushort_t*)A2u_raw;           // 9216 B
  ushort_t* Axl = (ushort_t*)(A2u_raw + 9216);  // 9216 B
  ushort_t* A2  = (ushort_t*)A2u_raw;           // stride 136 (17408 B), post-xin

  const int t = threadIdx.x;
  const int w = t >> 6, l = t & 63;
  const int lr = l & 15, lk = l >> 4;
  const int h = blockIdx.x >> 7;
  const int n0 = (blockIdx.x & 127) * 64;

#define STAGE_B(BUF, SRC, LDB, KOFF)                                          \
  {                                                                           \
    _Pragma("unroll")                                                         \
    for (int i = 0; i < 4; ++i) {                                             \
      int q = (i * 4 + w) * 64 + l;                                           \
      int row = q >> 3, s = q & 7;                                            \
      GLOAD_LDS16((SRC) + (size_t)(h * 128 + row) * (LDB) + (KOFF) +          \
                      ((s ^ (row & 7)) << 3),                                 \
                  (char*)(BUF) + (size_t)(i * 4 + w) * 1024);                 \
    }                                                                         \
  }

#define STAGE_BX(BUF, KC)                                                     \
  {                                                                           \
    _Pragma("unroll")                                                         \
    for (int i = 0; i < 4; ++i) {                                             \
      int q = (i * 4 + w) * 64 + l;                                           \
      int row = q >> 3, s = q & 7;                                            \
      int sw = (s ^ (row & 7)) << 3;                                          \
      int jj = h * 64 + (row & 63);                                           \
      int koff = (row < 64 ? 0 : 256) + (KC) * 64 + sw;                       \
      GLOAD_LDS16(wcvtT + (size_t)jj * 512 + koff,                            \
                  (char*)(BUF) + (size_t)(i * 4 + w) * 1024);                 \
    }                                                                         \
  }

#define MFMA_STEP(BUF, ACC, ALDS, KBASE, ASPLIT)                              \
  {                                                                           \
    _Pragma("unroll")                                                         \
    for (int kk = 0; kk < 2; ++kk) {                                          \
      int klog = (KBASE) + kk * 32 + lk * 8;                                  \
      int kp = (ASPLIT) ? (klog < 64 ? klog : klog - 64) : klog;              \
      bf16x8 af = *(const bf16x8*)&(ALDS)[(w * 16 + lr) * 136 + kp];          \
      _Pragma("unroll")                                                       \
      for (int cj = 0; cj < 8; ++cj) {                                        \
        int brow = cj * 16 + lr;                                              \
        int slot = (kk * 4 + lk) ^ (brow & 7);                                \
        bf16x8 bfr =                                                          \
            *(const bf16x8*)((const char*)(BUF) + brow * 128 + slot * 16);    \
        (ACC)[cj] = MFMA16(af, bfr, (ACC)[cj]);                               \
      }                                                                       \
    }                                                                         \
  }

#define MFMAX(BUF)                                                            \
  {                                                                           \
    _Pragma("unroll")                                                         \
    for (int kk = 0; kk < 2; ++kk) {                                          \
      bf16x8 ah = *(const bf16x8*)&Axh[(w * 16 + lr) * 72 + kk * 32 + lk * 8];\
      bf16x8 al = *(const bf16x8*)&Axl[(w * 16 + lr) * 72 + kk * 32 + lk * 8];\
      _Pragma("unroll")                                                       \
      for (int cj = 0; cj < 4; ++cj) {                                        \
        int rh = cj * 16 + lr;                                                \
        int slot = (kk * 4 + lk) ^ (rh & 7);                                  \
        bf16x8 bh = *(const bf16x8*)((const char*)(BUF) + rh * 128 + slot * 16);\
        bf16x8 bl = *(const bf16x8*)((const char*)(BUF) + (64 + rh) * 128 + slot * 16);\
        acc_x[cj] = MFMA16(ah, bh, acc_x[cj]);                                \
        acc_x[cj] = MFMA16(al, bh, acc_x[cj]);                                \
        acc_x[cj] = MFMA16(ah, bl, acc_x[cj]);                                \
      }                                                                       \
    }                                                                         \
  }

#define BAR() __builtin_amdgcn_s_barrier()
#define SCHED() __builtin_amdgcn_sched_barrier(0)
#define DRAIN_LGKM()                                                          \
  { asm volatile("s_waitcnt lgkmcnt(0)" ::: "memory"); SCHED(); }

  const int xrow = t >> 2;                 // 0..63
  const int xseg = (t & 3) << 4;           // 0/16/32/48
  const float* xbase = x + (size_t)(n0 + xrow) * 256 + xseg;
  float4 xr[4];

#define LOAD_X(KC)                                                            \
  {                                                                           \
    _Pragma("unroll")                                                         \
    for (int j = 0; j < 4; ++j) xr[j] = *(const float4*)(xbase + (KC) * 64 + j * 4); \
  }

#define CVT_AX()                                                              \
  {                                                                           \
    u16x8 hv0, hv1, lv0, lv1;                                                 \
    _Pragma("unroll")                                                         \
    for (int j = 0; j < 2; ++j) {                                             \
      float f4[8] = {xr[j*2].x, xr[j*2].y, xr[j*2].z, xr[j*2].w,              \
                     xr[j*2+1].x, xr[j*2+1].y, xr[j*2+1].z, xr[j*2+1].w};     \
      _Pragma("unroll")                                                       \
      for (int e = 0; e < 8; ++e) {                                           \
        ushort_t hi = f2bf(f4[e]);                                            \
        if (j == 0) { hv0[e] = hi; lv0[e] = f2bf(f4[e] - bf2f(hi)); }         \
        else        { hv1[e] = hi; lv1[e] = f2bf(f4[e] - bf2f(hi)); }         \
      }                                                                       \
    }                                                                         \
    *(u16x8*)&Axh[xrow * 72 + xseg]     = hv0;                                \
    *(u16x8*)&Axh[xrow * 72 + xseg + 8] = hv1;                                \
    *(u16x8*)&Axl[xrow * 72 + xseg]     = lv0;                                \
    *(u16x8*)&Axl[xrow * 72 + xseg + 8] = lv1;                                \
  }

  // ---- prologue ----
  cb_lds[t & 127] = cbias[h * 128 + (t & 127)];
  LOAD_X(0);
  STAGE_BX(Blds[0], 0);
  SCHED();                                 // pin B0 before B1 (vmcnt counting)
  STAGE_BX(Blds[1], 1);
  SCHED();
  f32x4 acc_x[4];
  #pragma unroll
  for (int cj = 0; cj < 4; ++cj) acc_x[cj] = (f32x4){0.f, 0.f, 0.f, 0.f};
  CVT_AX();                                // consume x0 (leaves B0,B1 in queue)
  SCHED();
  LOAD_X(1);                               // Q: [B0:4, B1:4, x1:4]
  asm volatile("s_waitcnt vmcnt(8)" ::: "memory");  // B0 done
  DRAIN_LGKM(); BAR(); SCHED();
  // chunk 0
  MFMAX(Blds[0]);
  DRAIN_LGKM(); BAR(); SCHED();
  STAGE_BX(Blds[0], 2);                    // Q: [B1, x1, B2]
  SCHED();
  CVT_AX();                                // consume x1 -> forces B1 done
  SCHED();
  LOAD_X(2);                               // Q: [B2:4, x2:4]
  DRAIN_LGKM(); BAR(); SCHED();
  // chunk 1
  MFMAX(Blds[1]);
  DRAIN_LGKM(); BAR(); SCHED();
  STAGE_BX(Blds[1], 3);                    // Q: [B2, x2, B3]
  SCHED();
  CVT_AX();                                // consume x2 -> forces B2 done
  SCHED();
  LOAD_X(3);                               // Q: [B3:4, x3:4]
  DRAIN_LGKM(); BAR(); SCHED();
  // chunk 2
  MFMAX(Blds[0]);
  DRAIN_LGKM(); BAR(); SCHED();
  STAGE_B(Blds[0], ctr3T, 192, 0);         // Q: [B3, x3, ctr0]
  SCHED();
  CVT_AX();                                // consume x3 -> forces B3 done
  DRAIN_LGKM(); BAR(); SCHED();
  // chunk 3
  MFMAX(Blds[1]);
  DRAIN_LGKM(); BAR(); SCHED();            // Blds[1], Ax free

  // write A1 (xin hi|lo) from acc_x — own wave's rows only
  STAGE_B(Blds[1], ctr3T, 192, 64);        // Q: [ctr0:4, ctr64:4]
  #pragma unroll
  for (int cj = 0; cj < 4; ++cj) {
    #pragma unroll
    for (int r = 0; r < 4; ++r) {
      int row = w * 16 + lk * 4 + r;
      int p = cj * 16 + lr;
      float v = acc_x[cj][r];
      ushort_t hi = f2bf(v);
      A1[row * 136 + p] = hi;
      A1[row * 136 + 64 + p] = f2bf(v - bf2f(hi));
    }
  }
  asm volatile("s_waitcnt vmcnt(4)" ::: "memory");  // ctr0 done
  DRAIN_LGKM(); BAR(); SCHED();

  // ---- logits: K=192, split hh/hl/lh over ctr3T ----
  f32x4 acc[8];
  #pragma unroll
  for (int cj = 0; cj < 8; ++cj) acc[cj] = (f32x4){0.f, 0.f, 0.f, 0.f};
  MFMA_STEP(Blds[0], acc, A1, 0, 1);       // L0
  DRAIN_LGKM(); BAR(); SCHED();
  STAGE_B(Blds[0], ctr3T, 192, 128);       // Q: [ctr64, ctr128]
  asm volatile("s_waitcnt vmcnt(4)" ::: "memory");
  BAR(); SCHED();
  MFMA_STEP(Blds[1], acc, A1, 64, 1);      // L1
  DRAIN_LGKM(); BAR(); SCHED();
  STAGE_B(Blds[1], W2bT, 128, 0);          // Q: [ctr128, W2k0]
  asm volatile("s_waitcnt vmcnt(4)" ::: "memory");
  BAR(); SCHED();
  MFMA_STEP(Blds[0], acc, A1, 128, 1);     // L2

  // ---- softmax (rows within wave; A2 rows own-wave) ----
  {
    float cbv[8];
    #pragma unroll
    for (int cj = 0; cj < 8; ++cj) cbv[cj] = cb_lds[cj * 16 + lr];
    #pragma unroll
    for (int r = 0; r < 4; ++r) {
      float v[8];
      float m = -1e30f;
      #pragma unroll
      for (int cj = 0; cj < 8; ++cj) {
        v[cj] = 2.f * acc[cj][r] + cbv[cj];
        m = fmaxf(m, v[cj]);
      }
      m = fmaxf(m, __shfl_xor(m, 1, 64));
      m = fmaxf(m, __shfl_xor(m, 2, 64));
      m = fmaxf(m, __shfl_xor(m, 4, 64));
      m = fmaxf(m, __shfl_xor(m, 8, 64));
      float s = 0.f;
      #pragma unroll
      for (int cj = 0; cj < 8; ++cj) {
        v[cj] = __expf(v[cj] - m);
        s += v[cj];
      }
      s += __shfl_xor(s, 1, 64);
      s += __shfl_xor(s, 2, 64);
      s += __shfl_xor(s, 4, 64);
      s += __shfl_xor(s, 8, 64);
      float inv = 1.f / s;
      int row = w * 16 + lk * 4 + r;
      #pragma unroll
      for (int cj = 0; cj < 8; ++cj)
        A2[row * 136 + cj * 16 + lr] = f2bf(v[cj] * inv);
    }
  }
  DRAIN_LGKM(); BAR(); SCHED();            // Blds[0] free

  f32x4 accT[8];
  #pragma unroll
  for (int cj = 0; cj < 8; ++cj) accT[cj] = (f32x4){0.f, 0.f, 0.f, 0.f};
  STAGE_B(Blds[0], W2bT, 128, 64);         // Q: [W2k0, W2k64]
  asm volatile("s_waitcnt vmcnt(4)" ::: "memory");
  BAR(); SCHED();
  MFMA_STEP(Blds[1], accT, A2, 0, 0);      // T0
  DRAIN_LGKM();
  asm volatile("s_waitcnt vmcnt(0)" ::: "memory");
  BAR(); SCHED();
  MFMA_STEP(Blds[0], accT, A2, 64, 0);     // T1

  // ---- epilogue: ho = xin(f32 regs)*t1 + t2 ; bounce via Blds[1] ----
  #pragma unroll
  for (int cj = 0; cj < 4; ++cj) {
    #pragma unroll
    for (int r = 0; r < 4; ++r) {
      int row = w * 16 + lk * 4 + r;
      int p = cj * 16 + lr;
      float hov = acc_x[cj][r] * accT[cj][r] + accT[cj + 4][r];
      ((ushort_t*)Blds[1])[row * 64 + p] = f2bf(hov);
    }
  }
  DRAIN_LGKM(); BAR(); SCHED();
  #pragma unroll
  for (int i = 0; i < 2; ++i) {
    int q = i * 256 + t;
    int row = q >> 3, s = q & 7;
    uint4 v = *(const uint4*)((const char*)Blds[1] + row * 128 + s * 16);
    *(uint4*)(ho2 + ((size_t)h * NROWS + n0 + row) * 64 + s * 8) = v;
  }
#undef STAGE_B
#undef STAGE_BX
#undef MFMA_STEP
#undef MFMAX
#undef BAR
#undef SCHED
#undef DRAIN_LGKM
#undef LOAD_X
#undef CVT_AX
}

// ---------------------------------------------------------------------------
extern "C" void kernel_launch(void* const* d_in, const int* in_sizes, int n_in,
                              void* d_out, int out_size, void* d_ws, size_t ws_size,
                              hipStream_t stream) {
  (void)in_sizes; (void)n_in; (void)out_size; (void)ws_size;
  const float* x    = (const float*)d_in[0];
  const float* ctrs = (const float*)d_in[1];
  const float* Wv   = (const float*)d_in[2];
  const float* Ov   = (const float*)d_in[3];
  const float* Wq   = (const float*)d_in[4];
  const float* Wo   = (const float*)d_in[5];
  float* out = (float*)d_out;

  char* wsb = (char*)d_ws;
  ushort_t* wcvtT = (ushort_t*)wsb;                   // [0, 524288)
  ushort_t* ctr3T = (ushort_t*)(wsb + 524288);        // [524288, 917504)
  float*    cb    = (float*)   (wsb + 917504);        // [917504, 921600)
  ushort_t* W2bT  = (ushort_t*)(wsb + 921600);        // [921600, 1183744)
  ushort_t* WoT   = (ushort_t*)(wsb + 1183744);       // [1183744, 1445888)
  ushort_t* ho2   = (ushort_t*)(wsb + 2097152);       // [2 MiB, 2 MiB + 8 MiB)

  prep_kernel<<<1536, 256, 0, stream>>>(Wq, ctrs, Wo, Wv, Ov,
                                        wcvtT, ctr3T, cb, WoT, W2bT);
  // xin GEMM + RBF softmax mixture fused -> ho2 flat (h,N,p)
  fused_all_kernel<<<NH * 128, 256, 0, stream>>>(x, wcvtT, ctr3T, cb, W2bT, ho2);
  // out = ho2_view(8192x512) @ Wo (bf16, K=512)
  mfma_gemm_kernel<0, 1><<<dim3(4, 64), 256, 0, stream>>>(ho2, WoT, out, 512, 512);
}

// Round 9
// 46.112 us; speedup vs baseline: 4.5327x; 1.0905x over previous
//
#include <hip/hip_runtime.h>
#include <math.h>

#define NROWS 8192
#define DIN   256
#define NH    8
#define NC    128
#define DOUT  256

typedef unsigned short ushort_t;
typedef __attribute__((ext_vector_type(8))) short bf16x8;
typedef __attribute__((ext_vector_type(4))) float f32x4;
typedef __attribute__((ext_vector_type(8))) unsigned short u16x8;

static __device__ __forceinline__ ushort_t f2bf(float f) {
  union { float f; unsigned u; } v; v.f = f;
  unsigned r = v.u + 0x7fffu + ((v.u >> 16) & 1u);
  return (ushort_t)(r >> 16);
}
static __device__ __forceinline__ float bf2f(ushort_t h) {
  union { unsigned u; float f; } v; v.u = ((unsigned)h) << 16;
  return v.f;
}

#define MFMA16(a, b, c) __builtin_amdgcn_mfma_f32_16x16x32_bf16((a), (b), (c), 0, 0, 0)
#define GLOAD_LDS16(g, l)                                                     \
  __builtin_amdgcn_global_load_lds(                                           \
      (const __attribute__((address_space(1))) void*)(g),                     \
      (__attribute__((address_space(3))) void*)(l), 16, 0, 0)

// ---------------------------------------------------------------------------
// Merged prep (grid 1536 x 256):
//  [0,512):    Wq (256,64,8) -> wcvtT [j=h*64+p][512] = [hi(256)|lo(256)]
//  [512,768):  ctrs -> ctr3T [h*128+c][192] (K=[hi|lo|hi]) + cbias
//  [768,1280): Wo (512,256) -> WoT [n][512]
//  [1280,1536): Wv/Ov -> W2bT [h*128+n][128]
// ---------------------------------------------------------------------------
__global__ __launch_bounds__(256) void prep_kernel(
    const float* __restrict__ Wq, const float* __restrict__ ctrs,
    const float* __restrict__ Wo, const float* __restrict__ Wv,
    const float* __restrict__ Ov, ushort_t* __restrict__ wcvtT,
    ushort_t* __restrict__ ctr3T, float* __restrict__ cbias,
    ushort_t* __restrict__ WoT, ushort_t* __restrict__ W2bT) {
  int bid = blockIdx.x;
  int t = threadIdx.x;
  if (bid < 512) {
    int j = bid, k = t;
    int h = j >> 6, p = j & 63;
    float v = Wq[((size_t)k * 64 + p) * 8 + h];
    ushort_t hi = f2bf(v), lo = f2bf(v - bf2f(hi));
    wcvtT[(size_t)j * 512 + k]       = hi;
    wcvtT[(size_t)j * 512 + 256 + k] = lo;
  } else if (bid < 768) {
    int idx = (bid - 512) * 4 + (t >> 6);   // h*128+c
    int p = t & 63;
    float v = ctrs[(size_t)idx * 64 + p];
    float sq = v * v;
    #pragma unroll
    for (int off = 32; off >= 1; off >>= 1) sq += __shfl_xor(sq, off, 64);
    if (p == 0) cbias[idx] = -sq;
    ushort_t hi = f2bf(v), lo = f2bf(v - bf2f(hi));
    ctr3T[(size_t)idx * 192 + p]       = hi;
    ctr3T[(size_t)idx * 192 + 64 + p]  = lo;
    ctr3T[(size_t)idx * 192 + 128 + p] = hi;
  } else if (bid < 1280) {
    int k = bid - 768;    // 0..511
    int n = t;            // 0..255
    WoT[(size_t)n * 512 + k] = f2bf(Wo[(size_t)k * 256 + n]);
  } else {
    int b = (bid - 1280) * 4 + (t >> 6);   // h*128 + c, 0..1023
    int p = t & 63;
    int h = b >> 7, c = b & 127;
    const float* wv = Wv + (size_t)b * 4096;
    float acc = 0.f;
    #pragma unroll 8
    for (int g = 0; g < 64; ++g) acc += wv[g * 64 + p];
    W2bT[((size_t)h * 128 + p) * 128 + c]      = f2bf(acc);
    W2bT[((size_t)h * 128 + 64 + p) * 128 + c] = f2bf(Ov[(size_t)b * 64 + p]);
  }
}

// ---------------------------------------------------------------------------
// gemm2: out[8192 x 256] = ho2_view[8192 x 512] @ WoT[256 x 512]^T
// BM=64 BN=64 BK=64, 256 threads (4 waves 2x2, wave tile 32x32).
// grid = dim3(4, 128) = 512 blocks (2/CU) so staging overlaps across blocks.
// ---------------------------------------------------------------------------
__global__ __launch_bounds__(256) void gemm2_kernel(
    const ushort_t* __restrict__ A, const ushort_t* __restrict__ Bt,
    float* __restrict__ out) {
  __shared__ ushort_t At[64 * 64];
  __shared__ ushort_t Bl[64 * 64];
  const int t = threadIdx.x;
  const int w = t >> 6, l = t & 63;
  const int wr = w >> 1, wc = w & 1;
  const int m0 = blockIdx.y * 64, n0 = blockIdx.x * 64;
  const int lr = l & 15, lk = l >> 4;

  f32x4 acc[2][2];
  #pragma unroll
  for (int a = 0; a < 2; ++a)
    #pragma unroll
    for (int b = 0; b < 2; ++b) acc[a][b] = (f32x4){0.f, 0.f, 0.f, 0.f};

  for (int k0 = 0; k0 < 512; k0 += 64) {
    #pragma unroll
    for (int i = 0; i < 2; ++i) {
      int q = (i * 4 + w) * 64 + l;
      int row = q >> 3, s = q & 7;
      int kl = k0 + ((s ^ (row & 7)) << 3);
      GLOAD_LDS16(A + (size_t)(m0 + row) * 512 + kl,
                  (char*)At + (size_t)(i * 4 + w) * 1024);
    }
    #pragma unroll
    for (int i = 0; i < 2; ++i) {
      int q = (i * 4 + w) * 64 + l;
      int row = q >> 3, s = q & 7;
      int kl = k0 + ((s ^ (row & 7)) << 3);
      GLOAD_LDS16(Bt + (size_t)(n0 + row) * 512 + kl,
                  (char*)Bl + (size_t)(i * 4 + w) * 1024);
    }
    __syncthreads();
    #pragma unroll
    for (int kk = 0; kk < 2; ++kk) {
      bf16x8 af[2], bfr[2];
      #pragma unroll
      for (int a = 0; a < 2; ++a) {
        int row = wr * 32 + a * 16 + lr;
        int s = (kk * 4 + lk) ^ (row & 7);
        af[a] = *(const bf16x8*)((const char*)At + row * 128 + s * 16);
      }
      #pragma unroll
      for (int b = 0; b < 2; ++b) {
        int row = wc * 32 + b * 16 + lr;
        int s = (kk * 4 + lk) ^ (row & 7);
        bfr[b] = *(const bf16x8*)((const char*)Bl + row * 128 + s * 16);
      }
      #pragma unroll
      for (int a = 0; a < 2; ++a)
        #pragma unroll
        for (int b = 0; b < 2; ++b)
          acc[a][b] = MFMA16(af[a], bfr[b], acc[a][b]);
    }
    __syncthreads();
  }
  #pragma unroll
  for (int a = 0; a < 2; ++a) {
    #pragma unroll
    for (int b = 0; b < 2; ++b) {
      #pragma unroll
      for (int r = 0; r < 4; ++r) {
        int rowg = m0 + wr * 32 + a * 16 + lk * 4 + r;
        int colg = n0 + wc * 32 + b * 16 + lr;
        out[(size_t)rowg * 256 + colg] = acc[a][b][r];
      }
    }
  }
}

// ---------------------------------------------------------------------------
// Fused-all: xin = x@Wq (split-bf16 MFMA, 4 chunks) -> logits (split-bf16
// MFMA, K=192) -> in-reg softmax -> T = a@W2 (bf16, K=128) -> ho = xin*t1+t2
// -> FLAT (h,N,p) bf16 write.
// LDS lifetime union (one 18.4 KB buffer): Axh/Axl (xin phase, dies at the
// barrier after chunk 3) -> A1 (written from acc_x after that barrier, read
// L0..L2) -> A2 (written after L2's lgkm drain at own-wave rows, read T0/T1).
// Every cross-wave handoff sits behind an existing DRAIN+BAR; A1->A2 is
// own-wave rows with in-order DS ops. 51.7 KB LDS -> 3 blocks/CU.
// ---------------------------------------------------------------------------
__global__ __launch_bounds__(256, 3) void fused_all_kernel(
    const float* __restrict__ x,          // [8192][256] f32
    const ushort_t* __restrict__ wcvtT,   // [512][512] hi|lo
    const ushort_t* __restrict__ ctr3T,   // [1024][192]
    const float* __restrict__ cbias,      // [1024]
    const ushort_t* __restrict__ W2bT,    // [1024][128]
    ushort_t* __restrict__ ho2) {         // flat (h,N,p)
  __shared__ __align__(16) char Au_raw[18432];  // union: Axh+Axl | A1 | A2
  __shared__ char Blds[2][16384];               // B buf: [128 rows][8 slots][16B]
  __shared__ float cb_lds[128];

  ushort_t* Axh = (ushort_t*)Au_raw;            // [64][72], 9216 B
  ushort_t* Axl = (ushort_t*)(Au_raw + 9216);   // [64][72], 9216 B
  ushort_t* A1  = (ushort_t*)Au_raw;            // [64][136] hi|lo, 17408 B
  ushort_t* A2  = (ushort_t*)Au_raw;            // [64][136] assignments

  const int t = threadIdx.x;
  const int w = t >> 6, l = t & 63;
  const int lr = l & 15, lk = l >> 4;
  const int h = blockIdx.x >> 7;
  const int n0 = (blockIdx.x & 127) * 64;

#define STAGE_B(BUF, SRC, LDB, KOFF)                                          \
  {                                                                           \
    _Pragma("unroll")                                                         \
    for (int i = 0; i < 4; ++i) {                                             \
      int q = (i * 4 + w) * 64 + l;                                           \
      int row = q >> 3, s = q & 7;                                            \
      GLOAD_LDS16((SRC) + (size_t)(h * 128 + row) * (LDB) + (KOFF) +          \
                      ((s ^ (row & 7)) << 3),                                 \
                  (char*)(BUF) + (size_t)(i * 4 + w) * 1024);                 \
    }                                                                         \
  }

#define STAGE_BX(BUF, KC)                                                     \
  {                                                                           \
    _Pragma("unroll")                                                         \
    for (int i = 0; i < 4; ++i) {                                             \
      int q = (i * 4 + w) * 64 + l;                                           \
      int row = q >> 3, s = q & 7;                                            \
      int sw = (s ^ (row & 7)) << 3;                                          \
      int jj = h * 64 + (row & 63);                                           \
      int koff = (row < 64 ? 0 : 256) + (KC) * 64 + sw;                       \
      GLOAD_LDS16(wcvtT + (size_t)jj * 512 + koff,                            \
                  (char*)(BUF) + (size_t)(i * 4 + w) * 1024);                 \
    }                                                                         \
  }

#define MFMA_STEP(BUF, ACC, ALDS, KBASE, ASPLIT)                              \
  {                                                                           \
    _Pragma("unroll")                                                         \
    for (int kk = 0; kk < 2; ++kk) {                                          \
      int klog = (KBASE) + kk * 32 + lk * 8;                                  \
      int kp = (ASPLIT) ? (klog < 64 ? klog : klog - 64) : klog;              \
      bf16x8 af = *(const bf16x8*)&(ALDS)[(w * 16 + lr) * 136 + kp];          \
      _Pragma("unroll")                                                       \
      for (int cj = 0; cj < 8; ++cj) {                                        \
        int brow = cj * 16 + lr;                                              \
        int slot = (kk * 4 + lk) ^ (brow & 7);                                \
        bf16x8 bfr =                                                          \
            *(const bf16x8*)((const char*)(BUF) + brow * 128 + slot * 16);    \
        (ACC)[cj] = MFMA16(af, bfr, (ACC)[cj]);                               \
      }                                                                       \
    }                                                                         \
  }

#define MFMAX(BUF)                                                            \
  {                                                                           \
    _Pragma("unroll")                                                         \
    for (int kk = 0; kk < 2; ++kk) {                                          \
      bf16x8 ah = *(const bf16x8*)&Axh[(w * 16 + lr) * 72 + kk * 32 + lk * 8];\
      bf16x8 al = *(const bf16x8*)&Axl[(w * 16 + lr) * 72 + kk * 32 + lk * 8];\
      _Pragma("unroll")                                                       \
      for (int cj = 0; cj < 4; ++cj) {                                        \
        int rh = cj * 16 + lr;                                                \
        int slot = (kk * 4 + lk) ^ (rh & 7);                                  \
        bf16x8 bh = *(const bf16x8*)((const char*)(BUF) + rh * 128 + slot * 16);\
        bf16x8 bl = *(const bf16x8*)((const char*)(BUF) + (64 + rh) * 128 + slot * 16);\
        acc_x[cj] = MFMA16(ah, bh, acc_x[cj]);                                \
        acc_x[cj] = MFMA16(al, bh, acc_x[cj]);                                \
        acc_x[cj] = MFMA16(ah, bl, acc_x[cj]);                                \
      }                                                                       \
    }                                                                         \
  }

#define BAR() __builtin_amdgcn_s_barrier()
#define SCHED() __builtin_amdgcn_sched_barrier(0)
#define DRAIN_LGKM()                                                          \
  { asm volatile("s_waitcnt lgkmcnt(0)" ::: "memory"); SCHED(); }

  const int xrow = t >> 2;                 // 0..63
  const int xseg = (t & 3) << 4;           // 0/16/32/48
  const float* xbase = x + (size_t)(n0 + xrow) * 256 + xseg;
  float4 xr[4];

#define LOAD_X(KC)                                                            \
  {                                                                           \
    _Pragma("unroll")                                                         \
    for (int j = 0; j < 4; ++j) xr[j] = *(const float4*)(xbase + (KC) * 64 + j * 4); \
  }

#define CVT_AX()                                                              \
  {                                                                           \
    u16x8 hv0, hv1, lv0, lv1;                                                 \
    _Pragma("unroll")                                                         \
    for (int j = 0; j < 2; ++j) {                                             \
      float f4[8] = {xr[j*2].x, xr[j*2].y, xr[j*2].z, xr[j*2].w,              \
                     xr[j*2+1].x, xr[j*2+1].y, xr[j*2+1].z, xr[j*2+1].w};     \
      _Pragma("unroll")                                                       \
      for (int e = 0; e < 8; ++e) {                                           \
        ushort_t hi = f2bf(f4[e]);                                            \
        if (j == 0) { hv0[e] = hi; lv0[e] = f2bf(f4[e] - bf2f(hi)); }         \
        else        { hv1[e] = hi; lv1[e] = f2bf(f4[e] - bf2f(hi)); }         \
      }                                                                       \
    }                                                                         \
    *(u16x8*)&Axh[xrow * 72 + xseg]     = hv0;                                \
    *(u16x8*)&Axh[xrow * 72 + xseg + 8] = hv1;                                \
    *(u16x8*)&Axl[xrow * 72 + xseg]     = lv0;                                \
    *(u16x8*)&Axl[xrow * 72 + xseg + 8] = lv1;                                \
  }

  // ---- prologue ----
  cb_lds[t & 127] = cbias[h * 128 + (t & 127)];
  LOAD_X(0);
  STAGE_BX(Blds[0], 0);
  SCHED();                                 // pin B0 before B1 (vmcnt counting)
  STAGE_BX(Blds[1], 1);
  SCHED();
  f32x4 acc_x[4];
  #pragma unroll
  for (int cj = 0; cj < 4; ++cj) acc_x[cj] = (f32x4){0.f, 0.f, 0.f, 0.f};
  CVT_AX();                                // consume x0 (leaves B0,B1 in queue)
  SCHED();
  LOAD_X(1);                               // Q: [B0:4, B1:4, x1:4]
  asm volatile("s_waitcnt vmcnt(8)" ::: "memory");  // B0 done
  DRAIN_LGKM(); BAR(); SCHED();
  // chunk 0
  MFMAX(Blds[0]);
  DRAIN_LGKM(); BAR(); SCHED();
  STAGE_BX(Blds[0], 2);                    // Q: [B1, x1, B2]
  SCHED();
  CVT_AX();                                // consume x1 -> forces B1 done
  SCHED();
  LOAD_X(2);                               // Q: [B2:4, x2:4]
  DRAIN_LGKM(); BAR(); SCHED();
  // chunk 1
  MFMAX(Blds[1]);
  DRAIN_LGKM(); BAR(); SCHED();
  STAGE_BX(Blds[1], 3);                    // Q: [B2, x2, B3]
  SCHED();
  CVT_AX();                                // consume x2 -> forces B2 done
  SCHED();
  LOAD_X(3);                               // Q: [B3:4, x3:4]
  DRAIN_LGKM(); BAR(); SCHED();
  // chunk 2
  MFMAX(Blds[0]);
  DRAIN_LGKM(); BAR(); SCHED();
  STAGE_B(Blds[0], ctr3T, 192, 0);         // Q: [B3, x3, ctr0]
  SCHED();
  CVT_AX();                                // consume x3 -> forces B3 done
  DRAIN_LGKM(); BAR(); SCHED();
  // chunk 3
  MFMAX(Blds[1]);
  DRAIN_LGKM(); BAR(); SCHED();            // Blds[1], Ax free

  // write A1 (xin hi|lo) from acc_x — own wave's rows only (Ax now dead)
  STAGE_B(Blds[1], ctr3T, 192, 64);        // Q: [ctr0:4, ctr64:4]
  #pragma unroll
  for (int cj = 0; cj < 4; ++cj) {
    #pragma unroll
    for (int r = 0; r < 4; ++r) {
      int row = w * 16 + lk * 4 + r;
      int p = cj * 16 + lr;
      float v = acc_x[cj][r];
      ushort_t hi = f2bf(v);
      A1[row * 136 + p] = hi;
      A1[row * 136 + 64 + p] = f2bf(v - bf2f(hi));
    }
  }
  asm volatile("s_waitcnt vmcnt(4)" ::: "memory");  // ctr0 done
  DRAIN_LGKM(); BAR(); SCHED();

  // ---- logits: K=192, split hh/hl/lh over ctr3T ----
  f32x4 acc[8];
  #pragma unroll
  for (int cj = 0; cj < 8; ++cj) acc[cj] = (f32x4){0.f, 0.f, 0.f, 0.f};
  MFMA_STEP(Blds[0], acc, A1, 0, 1);       // L0
  DRAIN_LGKM(); BAR(); SCHED();
  STAGE_B(Blds[0], ctr3T, 192, 128);       // Q: [ctr64, ctr128]
  asm volatile("s_waitcnt vmcnt(4)" ::: "memory");
  BAR(); SCHED();
  MFMA_STEP(Blds[1], acc, A1, 64, 1);      // L1
  DRAIN_LGKM(); BAR(); SCHED();
  STAGE_B(Blds[1], W2bT, 128, 0);          // Q: [ctr128, W2k0]
  asm volatile("s_waitcnt vmcnt(4)" ::: "memory");
  BAR(); SCHED();
  MFMA_STEP(Blds[0], acc, A1, 128, 1);     // L2
  DRAIN_LGKM();                            // L2's A1 reads landed (in-regs)

  // ---- softmax (rows within wave; A2 rows own-wave, overwrites A1) ----
  {
    float cbv[8];
    #pragma unroll
    for (int cj = 0; cj < 8; ++cj) cbv[cj] = cb_lds[cj * 16 + lr];
    #pragma unroll
    for (int r = 0; r < 4; ++r) {
      float v[8];
      float m = -1e30f;
      #pragma unroll
      for (int cj = 0; cj < 8; ++cj) {
        v[cj] = 2.f * acc[cj][r] + cbv[cj];
        m = fmaxf(m, v[cj]);
      }
      m = fmaxf(m, __shfl_xor(m, 1, 64));
      m = fmaxf(m, __shfl_xor(m, 2, 64));
      m = fmaxf(m, __shfl_xor(m, 4, 64));
      m = fmaxf(m, __shfl_xor(m, 8, 64));
      float s = 0.f;
      #pragma unroll
      for (int cj = 0; cj < 8; ++cj) {
        v[cj] = __expf(v[cj] - m);
        s += v[cj];
      }
      s += __shfl_xor(s, 1, 64);
      s += __shfl_xor(s, 2, 64);
      s += __shfl_xor(s, 4, 64);
      s += __shfl_xor(s, 8, 64);
      float inv = 1.f / s;
      int row = w * 16 + lk * 4 + r;
      #pragma unroll
      for (int cj = 0; cj < 8; ++cj)
        A2[row * 136 + cj * 16 + lr] = f2bf(v[cj] * inv);
    }
  }
  DRAIN_LGKM();          // step-2 ds_reads + A2 writes drained
  BAR(); SCHED();        // now safe to overwrite Blds[0]

  f32x4 accT[8];
  #pragma unroll
  for (int cj = 0; cj < 8; ++cj) accT[cj] = (f32x4){0.f, 0.f, 0.f, 0.f};
  STAGE_B(Blds[0], W2bT, 128, 64);         // Q: [W2k0, W2k64]
  asm volatile("s_waitcnt vmcnt(4)" ::: "memory");
  BAR(); SCHED();
  MFMA_STEP(Blds[1], accT, A2, 0, 0);      // T0
  DRAIN_LGKM();
  asm volatile("s_waitcnt vmcnt(0)" ::: "memory");
  BAR(); SCHED();
  MFMA_STEP(Blds[0], accT, A2, 64, 0);     // T1

  // ---- epilogue: ho = xin(f32 regs)*t1 + t2 ; bounce via Blds[1] ----
  #pragma unroll
  for (int cj = 0; cj < 4; ++cj) {
    #pragma unroll
    for (int r = 0; r < 4; ++r) {
      int row = w * 16 + lk * 4 + r;
      int p = cj * 16 + lr;
      float hov = acc_x[cj][r] * accT[cj][r] + accT[cj + 4][r];
      ((ushort_t*)Blds[1])[row * 64 + p] = f2bf(hov);
    }
  }
  DRAIN_LGKM(); BAR(); SCHED();
  #pragma unroll
  for (int i = 0; i < 2; ++i) {
    int q = i * 256 + t;
    int row = q >> 3, s = q & 7;
    uint4 v = *(const uint4*)((const char*)Blds[1] + row * 128 + s * 16);
    *(uint4*)(ho2 + ((size_t)h * NROWS + n0 + row) * 64 + s * 8) = v;
  }
#undef STAGE_B
#undef STAGE_BX
#undef MFMA_STEP
#undef MFMAX
#undef BAR
#undef SCHED
#undef DRAIN_LGKM
#undef LOAD_X
#undef CVT_AX
}

// ---------------------------------------------------------------------------
extern "C" void kernel_launch(void* const* d_in, const int* in_sizes, int n_in,
                              void* d_out, int out_size, void* d_ws, size_t ws_size,
                              hipStream_t stream) {
  (void)in_sizes; (void)n_in; (void)out_size; (void)ws_size;
  const float* x    = (const float*)d_in[0];
  const float* ctrs = (const float*)d_in[1];
  const float* Wv   = (const float*)d_in[2];
  const float* Ov   = (const float*)d_in[3];
  const float* Wq   = (const float*)d_in[4];
  const float* Wo   = (const float*)d_in[5];
  float* out = (float*)d_out;

  char* wsb = (char*)d_ws;
  ushort_t* wcvtT = (ushort_t*)wsb;                   // [0, 524288)
  ushort_t* ctr3T = (ushort_t*)(wsb + 524288);        // [524288, 917504)
  float*    cb    = (float*)   (wsb + 917504);        // [917504, 921600)
  ushort_t* W2bT  = (ushort_t*)(wsb + 921600);        // [921600, 1183744)
  ushort_t* WoT   = (ushort_t*)(wsb + 1183744);       // [1183744, 1445888)
  ushort_t* ho2   = (ushort_t*)(wsb + 2097152);       // [2 MiB, 2 MiB + 8 MiB)

  prep_kernel<<<1536, 256, 0, stream>>>(Wq, ctrs, Wo, Wv, Ov,
                                        wcvtT, ctr3T, cb, WoT, W2bT);
  // xin GEMM + RBF softmax mixture fused -> ho2 flat (h,N,p)
  fused_all_kernel<<<NH * 128, 256, 0, stream>>>(x, wcvtT, ctr3T, cb, W2bT, ho2);
  // out = ho2_view(8192x512) @ Wo (bf16, K=512)
  gemm2_kernel<<<dim3(4, 128), 256, 0, stream>>>(ho2, WoT, out);
}